// Round 3
// baseline (894.277 us; speedup 1.0000x reference)
//
#include <hip/hip_runtime.h>

typedef unsigned short u16;
typedef __attribute__((ext_vector_type(8))) short short8;
typedef __attribute__((ext_vector_type(4))) float f32x4;

#define MFMA16(a, b, c) __builtin_amdgcn_mfma_f32_16x16x32_bf16(a, b, c, 0, 0, 0)

__device__ __forceinline__ float bf2f(u16 u) {
    return __uint_as_float(((unsigned)u) << 16);
}
__device__ __forceinline__ u16 f2bf(float f) {
    unsigned u = __float_as_uint(f);
    u += 0x7fff + ((u >> 16) & 1);
    return (u16)(u >> 16);
}

// ---------------------------------------------------------------------------
// Fold kernels: collapse (proj -> concat -> proj) into single bf16 weights,
// stored TRANSPOSED ([N][K]) for the GEMM's B-operand fragment reads.
// Head-concat col map: c=h*64+j; j<32 -> content h*32+j ; j>=32 -> other h*32+(j-32).
// mapC(cc)=(cc>>5)*64+(cc&31), mapS=mapC+32.  All source weights are f32.
// ---------------------------------------------------------------------------

// WQ3T[512][768]: k<256: w_qc@wqC ; 256..511: w_qp@wqC ; 512..767: w_qs@wqS (x 1/8)
__global__ __launch_bounds__(256) void fold_q(const float* __restrict__ w_qc,
                                              const float* __restrict__ w_qp,
                                              const float* __restrict__ w_qs,
                                              const float* __restrict__ wq,
                                              u16* __restrict__ WQ3T) {
    int t = blockIdx.x * 256 + threadIdx.x; // 49152 threads
    int o = t / 96;
    int k8 = (t % 96) * 8;
    const float* wsrc;
    int kbase, sOff = 0;
    if (k8 < 256) { wsrc = w_qc; kbase = k8; }
    else if (k8 < 512) { wsrc = w_qp; kbase = k8 - 256; }
    else { wsrc = w_qs; kbase = k8 - 512; sOff = 32; }
    float acc[8] = {0, 0, 0, 0, 0, 0, 0, 0};
    for (int c4 = 0; c4 < 256; c4 += 4) {
        float wvv[4];
#pragma unroll
        for (int e = 0; e < 4; e++) {
            int cc = c4 + e;
            int map = (cc >> 5) * 64 + (cc & 31) + sOff;
            wvv[e] = wq[(size_t)map * 512 + o];
        }
#pragma unroll
        for (int i = 0; i < 8; i++) {
            float4 tv = *(const float4*)(wsrc + (size_t)(kbase + i) * 256 + c4);
            acc[i] += tv.x * wvv[0] + tv.y * wvv[1] + tv.z * wvv[2] + tv.w * wvv[3];
        }
    }
    u16 outv[8];
#pragma unroll
    for (int i = 0; i < 8; i++) outv[i] = f2bf(acc[i] * 0.125f);
    *(uint4*)(WQ3T + (size_t)o * 768 + k8) = *(uint4*)outv;
}

// WK2T[512][512]: k<256: w_kc@wkC ; k>=256: w_kp@(wkC+wkS)
__global__ __launch_bounds__(256) void fold_k(const float* __restrict__ w_kc,
                                              const float* __restrict__ w_kp,
                                              const float* __restrict__ wk,
                                              u16* __restrict__ WK2T) {
    int t = blockIdx.x * 256 + threadIdx.x; // 32768 threads
    int o = t / 64;
    int k8 = (t % 64) * 8;
    bool second = k8 >= 256;
    const float* wsrc = second ? w_kp : w_kc;
    int kbase = second ? k8 - 256 : k8;
    float acc[8] = {0, 0, 0, 0, 0, 0, 0, 0};
    for (int c4 = 0; c4 < 256; c4 += 4) {
        float wvv[4];
#pragma unroll
        for (int e = 0; e < 4; e++) {
            int cc = c4 + e;
            int mc = (cc >> 5) * 64 + (cc & 31);
            float w0 = wk[(size_t)mc * 512 + o];
            if (second) w0 += wk[(size_t)(mc + 32) * 512 + o];
            wvv[e] = w0;
        }
#pragma unroll
        for (int i = 0; i < 8; i++) {
            float4 tv = *(const float4*)(wsrc + (size_t)(kbase + i) * 256 + c4);
            acc[i] += tv.x * wvv[0] + tv.y * wvv[1] + tv.z * wvv[2] + tv.w * wvv[3];
        }
    }
    u16 outv[8];
#pragma unroll
    for (int i = 0; i < 8; i++) outv[i] = f2bf(acc[i]);
    *(uint4*)(WK2T + (size_t)o * 512 + k8) = *(uint4*)outv;
}

// WV2T[256][256] = (w_v @ wv)^T
__global__ __launch_bounds__(256) void fold_v(const float* __restrict__ w_v,
                                              const float* __restrict__ wv_w,
                                              u16* __restrict__ WV2T) {
    int t = blockIdx.x * 256 + threadIdx.x; // 8192 threads
    int o = t / 32;
    int k8 = (t % 32) * 8;
    float acc[8] = {0, 0, 0, 0, 0, 0, 0, 0};
    for (int c4 = 0; c4 < 256; c4 += 4) {
        float wvv[4];
#pragma unroll
        for (int e = 0; e < 4; e++) wvv[e] = wv_w[(size_t)(c4 + e) * 256 + o];
#pragma unroll
        for (int i = 0; i < 8; i++) {
            float4 tv = *(const float4*)(w_v + (size_t)(k8 + i) * 256 + c4);
            acc[i] += tv.x * wvv[0] + tv.y * wvv[1] + tv.z * wvv[2] + tv.w * wvv[3];
        }
    }
    u16 outv[8];
#pragma unroll
    for (int i = 0; i < 8; i++) outv[i] = f2bf(acc[i]);
    *(uint4*)(WV2T + (size_t)o * 256 + k8) = *(uint4*)outv;
}

// folded biases (f32): BQF[512], BKF[512], BVF[256]
__global__ __launch_bounds__(256) void fold_bias(
    const float* b_qc, const float* b_qp, const float* b_qs, const float* wq, const float* bq,
    const float* b_kc, const float* b_kp, const float* wk, const float* bk,
    const float* b_v, const float* wv_w, const float* bv,
    float* BQF, float* BKF, float* BVF) {
    int t = blockIdx.x * 256 + threadIdx.x; // 1280 threads
    if (t < 512) {
        int o = t;
        float a = bq[o];
        for (int cc = 0; cc < 256; cc++) {
            int mc = (cc >> 5) * 64 + (cc & 31);
            a += (b_qc[cc] + b_qp[cc]) * wq[(size_t)mc * 512 + o];
            a += b_qs[cc] * wq[(size_t)(mc + 32) * 512 + o];
        }
        BQF[o] = a * 0.125f;
    } else if (t < 1024) {
        int o = t - 512;
        float a = bk[o];
        for (int cc = 0; cc < 256; cc++) {
            int mc = (cc >> 5) * 64 + (cc & 31);
            a += (b_kc[cc] + b_kp[cc]) * wk[(size_t)mc * 512 + o];
            a += b_kp[cc] * wk[(size_t)(mc + 32) * 512 + o];
        }
        BKF[o] = a;
    } else if (t < 1280) {
        int o = t - 1024;
        float a = bv[o];
        for (int cc = 0; cc < 256; cc++) a += b_v[cc] * wv_w[(size_t)cc * 256 + o];
        BVF[o] = a;
    }
}

// f32 -> bf16 transpose: dst[C][R] = src[R][C], 32x32 tiles
__global__ __launch_bounds__(256) void transpose_f2b(const float* __restrict__ src,
                                                     u16* __restrict__ dst, int R, int C) {
    __shared__ float tile[32][33];
    int c0 = blockIdx.x * 32, r0 = blockIdx.y * 32;
    int t = threadIdx.x;
    int j = t & 31, i0 = (t >> 5) * 4;
#pragma unroll
    for (int ii = 0; ii < 4; ii++)
        tile[i0 + ii][j] = src[(size_t)(r0 + i0 + ii) * C + c0 + j];
    __syncthreads();
    int i2 = t & 31, j0 = (t >> 5) * 4;
#pragma unroll
    for (int jj = 0; jj < 4; jj++)
        dst[(size_t)(c0 + j0 + jj) * R + r0 + i2] = f2bf(tile[i2][j0 + jj]);
}

// ---------------------------------------------------------------------------
// Main GEMM: C[M][N] = concat_parts(A)[M][K] @ BT[N][K]^T + bias.
// 128x128 tile, BK=32, 4 waves each 64x64 (4x4 mfma 16x16x32).
// A: f32 (a_f32=1) or bf16; staged to bf16 LDS. BT: bf16 (preprocessed).
// When astride==256, part p=k0>>8 selects A0/A1/A2 (row stride 256); else A0.
// mode: 0 = bf16 store C[M][N]; 1 = relu+bf16 store; 2 = scatter bf16 into
// V-transpose layout vhT[b][h][d][k] (row=k*16+b, col=h*32+d).
// ---------------------------------------------------------------------------
#define APAD 40
__global__ __launch_bounds__(256) void gemm_bt(
    const void* __restrict__ A0v, const void* __restrict__ A1v, const void* __restrict__ A2v,
    int astride, int a_f32, const u16* __restrict__ BT, const float* __restrict__ bias,
    u16* __restrict__ C, int M, int N, int K, int mode) {
    __shared__ u16 As[128 * APAD];
    __shared__ u16 Bs[128 * APAD];
    int tid = threadIdx.x;
    int wave = tid >> 6, lane = tid & 63;
    int l15 = lane & 15, quad = lane >> 4;
    int wm = (wave >> 1) * 64, wn = (wave & 1) * 64;
    int gm0 = blockIdx.x * 128, gn0 = blockIdx.y * 128;
    f32x4 acc[4][4] = {};
    for (int k0 = 0; k0 < K; k0 += 32) {
        const void* ap;
        int kin;
        if (astride == 256) {
            int p = k0 >> 8;
            ap = (p == 0) ? A0v : ((p == 1) ? A1v : A2v);
            kin = k0 & 255;
        } else {
            ap = A0v;
            kin = k0;
        }
#pragma unroll
        for (int i = 0; i < 2; i++) {
            int idx = tid * 2 + i;
            int row = idx >> 2, seg = (idx & 3) * 8;
            int grow = gm0 + row;
            u16 tmp[8];
            if (a_f32) {
                float vv[8] = {0.f, 0.f, 0.f, 0.f, 0.f, 0.f, 0.f, 0.f};
                if (grow < M) {
                    const float* apf = (const float*)ap;
                    float4 u0 = *(const float4*)(apf + (size_t)grow * astride + kin + seg);
                    float4 u1 = *(const float4*)(apf + (size_t)grow * astride + kin + seg + 4);
                    vv[0] = u0.x; vv[1] = u0.y; vv[2] = u0.z; vv[3] = u0.w;
                    vv[4] = u1.x; vv[5] = u1.y; vv[6] = u1.z; vv[7] = u1.w;
                }
#pragma unroll
                for (int e = 0; e < 8; e++) tmp[e] = f2bf(vv[e]);
            } else {
                uint4 v;
                v.x = v.y = v.z = v.w = 0;
                if (grow < M) v = *(const uint4*)((const u16*)ap + (size_t)grow * astride + kin + seg);
                *(uint4*)tmp = v;
            }
            *(uint4*)(&As[row * APAD + seg]) = *(uint4*)tmp;
            int nrow = gn0 + row;
            uint4 w = *(const uint4*)(BT + (size_t)nrow * K + k0 + seg);
            *(uint4*)(&Bs[row * APAD + seg]) = w;
        }
        __syncthreads();
        short8 afr[4], bfr[4];
#pragma unroll
        for (int i = 0; i < 4; i++)
            afr[i] = *(const short8*)(&As[(wm + i * 16 + l15) * APAD + quad * 8]);
#pragma unroll
        for (int j = 0; j < 4; j++)
            bfr[j] = *(const short8*)(&Bs[(wn + j * 16 + l15) * APAD + quad * 8]);
#pragma unroll
        for (int i = 0; i < 4; i++)
#pragma unroll
            for (int j = 0; j < 4; j++) acc[i][j] = MFMA16(afr[i], bfr[j], acc[i][j]);
        __syncthreads();
    }
#pragma unroll
    for (int i = 0; i < 4; i++) {
        int row = gm0 + wm + i * 16 + quad * 4;
#pragma unroll
        for (int j = 0; j < 4; j++) {
            int col = gn0 + wn + j * 16 + l15;
            float bvv = bias[col];
#pragma unroll
            for (int r = 0; r < 4; r++) {
                int grow = row + r;
                if (grow < M) {
                    float v = acc[i][j][r] + bvv;
                    if (mode == 1) v = fmaxf(v, 0.f);
                    if (mode == 2) {
                        int kk = grow >> 4, bb = grow & 15;
                        int hh = col >> 5, dd = col & 31;
                        C[(((size_t)bb * 8 + hh) * 32 + dd) * 2048 + kk] = f2bf(v);
                    } else {
                        C[(size_t)grow * N + col] = f2bf(v);
                    }
                }
            }
        }
    }
}

// ---------------------------------------------------------------------------
// Attention kernel A: per (qtile, h, b) — one pass over k: unnormalized
// exp-sum Z and unnormalized ctx (logits tiny -> no max subtraction needed);
// normalize in epilogue, store ctx (bf16) and 1/(8Z) (f32).
// ---------------------------------------------------------------------------
__global__ __launch_bounds__(256) void attn_a(const u16* __restrict__ qh,
                                              const u16* __restrict__ kh,
                                              const u16* __restrict__ vhT,
                                              u16* __restrict__ ctxbuf,
                                              float* __restrict__ z8inv) {
    int qt = blockIdx.x, h = blockIdx.y, b = blockIdx.z;
    __shared__ u16 Qt[64 * 72];
    __shared__ u16 Kc[128 * 72];
    __shared__ u16 Pt[64 * 136];
    __shared__ u16 VTc[32 * 136];
    int tid = threadIdx.x, wave = tid >> 6, lane = tid & 63;
    int l15 = lane & 15, quad = lane >> 4;
    int q0 = qt * 64;
#pragma unroll
    for (int i = 0; i < 2; i++) {
        int idx = tid * 2 + i;
        int row = idx >> 3, seg = (idx & 7) * 8;
        uint4 v;
        v.x = v.y = v.z = v.w = 0;
        int q = q0 + row;
        if (q < 300) v = *(const uint4*)(qh + ((size_t)q * 16 + b) * 512 + h * 64 + seg);
        *(uint4*)(&Qt[row * 72 + seg]) = v;
    }
    const f32x4 zf = {0.f, 0.f, 0.f, 0.f};
    f32x4 cacc[2] = {};
    float zrow[4] = {0.f, 0.f, 0.f, 0.f};
    for (int kc0 = 0; kc0 < 2048; kc0 += 128) {
#pragma unroll
        for (int i = 0; i < 4; i++) {
            int idx = tid * 4 + i;
            int row = idx >> 3, seg = (idx & 7) * 8;
            *(uint4*)(&Kc[row * 72 + seg]) =
                *(const uint4*)(kh + ((size_t)(kc0 + row) * 16 + b) * 512 + h * 64 + seg);
        }
#pragma unroll
        for (int i = 0; i < 2; i++) {
            int idx = tid * 2 + i;
            int row = idx >> 4, seg = (idx & 15) * 8;
            *(uint4*)(&VTc[row * 136 + seg]) =
                *(const uint4*)(vhT + (((size_t)b * 8 + h) * 32 + row) * 2048 + kc0 + seg);
        }
        __syncthreads();
        f32x4 sacc[8];
#pragma unroll
        for (int t = 0; t < 8; t++) sacc[t] = zf;
#pragma unroll
        for (int d0 = 0; d0 < 64; d0 += 32) {
            short8 af = *(const short8*)(&Qt[(wave * 16 + l15) * 72 + d0 + quad * 8]);
#pragma unroll
            for (int t = 0; t < 8; t++) {
                short8 bf = *(const short8*)(&Kc[(t * 16 + l15) * 72 + d0 + quad * 8]);
                sacc[t] = MFMA16(af, bf, sacc[t]);
            }
        }
#pragma unroll
        for (int t = 0; t < 8; t++) {
#pragma unroll
            for (int r = 0; r < 4; r++) {
                float p = __expf(sacc[t][r]);
                zrow[r] += p;
                Pt[(wave * 16 + quad * 4 + r) * 136 + t * 16 + l15] = f2bf(p);
            }
        }
#pragma unroll
        for (int kk0 = 0; kk0 < 128; kk0 += 32) {
            short8 af = *(const short8*)(&Pt[(wave * 16 + l15) * 136 + kk0 + quad * 8]);
#pragma unroll
            for (int t = 0; t < 2; t++) {
                short8 bf = *(const short8*)(&VTc[(t * 16 + l15) * 136 + kk0 + quad * 8]);
                cacc[t] = MFMA16(af, bf, cacc[t]);
            }
        }
        __syncthreads();
    }
#pragma unroll
    for (int r = 0; r < 4; r++) {
        float z = zrow[r];
        z += __shfl_xor(z, 1);
        z += __shfl_xor(z, 2);
        z += __shfl_xor(z, 4);
        z += __shfl_xor(z, 8);
        zrow[r] = z;
    }
#pragma unroll
    for (int r = 0; r < 4; r++) {
        int q = q0 + wave * 16 + quad * 4 + r;
        if (q < 300) {
            float rz = 1.0f / zrow[r];
#pragma unroll
            for (int t = 0; t < 2; t++)
                ctxbuf[((size_t)q * 16 + b) * 256 + h * 32 + t * 16 + l15] = f2bf(cacc[t][r] * rz);
            if (l15 == 0) z8inv[((size_t)b * 8 + h) * 320 + q] = rz * 0.125f;
        }
    }
}

// ---------------------------------------------------------------------------
// Attention kernel B: per (kchunk, qtile, b) — loop all 8 heads, recompute
// logits, p = exp(s) * (1/(8Z)), accumulate head-average, write attn_avg (f32).
// ---------------------------------------------------------------------------
__global__ __launch_bounds__(256) void attn_b(const u16* __restrict__ qh,
                                              const u16* __restrict__ kh,
                                              const float* __restrict__ z8inv,
                                              float* __restrict__ out1) {
    int kc0 = blockIdx.x * 128, qt = blockIdx.y, b = blockIdx.z;
    __shared__ u16 Qt[64 * 72];
    __shared__ u16 Kc[128 * 72];
    int tid = threadIdx.x, wave = tid >> 6, lane = tid & 63;
    int l15 = lane & 15, quad = lane >> 4;
    int q0 = qt * 64;
    const f32x4 zf = {0.f, 0.f, 0.f, 0.f};
    float avg[8][4] = {};
    for (int h = 0; h < 8; h++) {
#pragma unroll
        for (int i = 0; i < 2; i++) {
            int idx = tid * 2 + i;
            int row = idx >> 3, seg = (idx & 7) * 8;
            uint4 v;
            v.x = v.y = v.z = v.w = 0;
            int q = q0 + row;
            if (q < 300) v = *(const uint4*)(qh + ((size_t)q * 16 + b) * 512 + h * 64 + seg);
            *(uint4*)(&Qt[row * 72 + seg]) = v;
        }
#pragma unroll
        for (int i = 0; i < 4; i++) {
            int idx = tid * 4 + i;
            int row = idx >> 3, seg = (idx & 7) * 8;
            *(uint4*)(&Kc[row * 72 + seg]) =
                *(const uint4*)(kh + ((size_t)(kc0 + row) * 16 + b) * 512 + h * 64 + seg);
        }
        __syncthreads();
        f32x4 sacc[8];
#pragma unroll
        for (int t = 0; t < 8; t++) sacc[t] = zf;
#pragma unroll
        for (int d0 = 0; d0 < 64; d0 += 32) {
            short8 af = *(const short8*)(&Qt[(wave * 16 + l15) * 72 + d0 + quad * 8]);
#pragma unroll
            for (int t = 0; t < 8; t++) {
                short8 bf = *(const short8*)(&Kc[(t * 16 + l15) * 72 + d0 + quad * 8]);
                sacc[t] = MFMA16(af, bf, sacc[t]);
            }
        }
        float zi[4];
#pragma unroll
        for (int r = 0; r < 4; r++) {
            int q = q0 + wave * 16 + quad * 4 + r;
            zi[r] = z8inv[((size_t)b * 8 + h) * 320 + (q < 319 ? q : 319)];
        }
#pragma unroll
        for (int t = 0; t < 8; t++)
#pragma unroll
            for (int r = 0; r < 4; r++) avg[t][r] += __expf(sacc[t][r]) * zi[r];
        __syncthreads();
    }
#pragma unroll
    for (int r = 0; r < 4; r++) {
        int q = q0 + wave * 16 + quad * 4 + r;
        if (q < 300) {
#pragma unroll
            for (int t = 0; t < 8; t++)
                out1[((size_t)b * 300 + q) * 2048 + kc0 + t * 16 + l15] = avg[t][r];
        }
    }
}

// residual add + LayerNorm over last dim (256). a: f32 or bf16; out: f32 or bf16.
__global__ __launch_bounds__(256) void ln_kernel(const void* __restrict__ a, int a_f32,
                                                 const u16* __restrict__ bres,
                                                 const float* __restrict__ g,
                                                 const float* __restrict__ be,
                                                 void* __restrict__ out, int out_f32) {
    int row = blockIdx.x, t = threadIdx.x;
    float av = a_f32 ? ((const float*)a)[(size_t)row * 256 + t]
                     : bf2f(((const u16*)a)[(size_t)row * 256 + t]);
    float v = av + bf2f(bres[(size_t)row * 256 + t]);
    float s = v, sq = v * v;
#pragma unroll
    for (int o = 32; o; o >>= 1) {
        s += __shfl_xor(s, o);
        sq += __shfl_xor(sq, o);
    }
    __shared__ float red[8];
    int wave = t >> 6, lane = t & 63;
    if (lane == 0) {
        red[wave] = s;
        red[4 + wave] = sq;
    }
    __syncthreads();
    s = red[0] + red[1] + red[2] + red[3];
    sq = red[4] + red[5] + red[6] + red[7];
    float mean = s * (1.f / 256.f);
    float var = sq * (1.f / 256.f) - mean * mean;
    float rs = rsqrtf(var + 1e-5f);
    float res = (v - mean) * rs * g[t] + be[t];
    if (out_f32) ((float*)out)[(size_t)row * 256 + t] = res;
    else ((u16*)out)[(size_t)row * 256 + t] = f2bf(res);
}

// ---------------------------------------------------------------------------
extern "C" void kernel_launch(void* const* d_in, const int* in_sizes, int n_in,
                              void* d_out, int out_size, void* d_ws, size_t ws_size,
                              hipStream_t stream) {
    (void)in_sizes; (void)n_in; (void)out_size; (void)ws_size;
    const float* tgt = (const float*)d_in[0];
    const float* mem = (const float*)d_in[1];
    const float* pos = (const float*)d_in[2];
    const float* qpos = (const float*)d_in[3];
    const float* qsine = (const float*)d_in[4];
    const float* w_qc = (const float*)d_in[5];
    const float* b_qc = (const float*)d_in[6];
    const float* w_qp = (const float*)d_in[7];
    const float* b_qp = (const float*)d_in[8];
    const float* w_kc = (const float*)d_in[9];
    const float* b_kc = (const float*)d_in[10];
    const float* w_kp = (const float*)d_in[11];
    const float* b_kp = (const float*)d_in[12];
    const float* w_v = (const float*)d_in[13];
    const float* b_v = (const float*)d_in[14];
    const float* w_qs = (const float*)d_in[15];
    const float* b_qs = (const float*)d_in[16];
    const float* wq = (const float*)d_in[17];
    const float* bq = (const float*)d_in[18];
    const float* wk = (const float*)d_in[19];
    const float* bk = (const float*)d_in[20];
    const float* wv_w = (const float*)d_in[21];
    const float* bv = (const float*)d_in[22];
    const float* wo = (const float*)d_in[23];
    const float* bo = (const float*)d_in[24];
    const float* w1 = (const float*)d_in[25];
    const float* b1 = (const float*)d_in[26];
    const float* w2 = (const float*)d_in[27];
    const float* b2 = (const float*)d_in[28];
    const float* g2 = (const float*)d_in[29];
    const float* be2 = (const float*)d_in[30];
    const float* g3 = (const float*)d_in[31];
    const float* be3 = (const float*)d_in[32];

    // --- workspace layout (peak 0x2B58000 = 45.6 MB) ---
    char* ws = (char*)d_ws;
    u16* WQ3T = (u16*)(ws + 0x000000);     // 512x768 bf16   (0xC0000)
    u16* WK2T = (u16*)(ws + 0x0C0000);     // 512x512        (0x80000)
    u16* WV2T = (u16*)(ws + 0x140000);     // 256x256        (0x20000)
    u16* WOT  = (u16*)(ws + 0x160000);     // 256x256        (0x20000)
    u16* W1T  = (u16*)(ws + 0x180000);     // 2048x256       (0x100000)
    u16* W2T  = (u16*)(ws + 0x280000);     // 256x2048       (0x100000)
    float* BQF = (float*)(ws + 0x380000);
    float* BKF = (float*)(ws + 0x381000);
    float* BVF = (float*)(ws + 0x382000);
    float* Z8  = (float*)(ws + 0x390000);  // 16x8x320 f32   (0x28000)
    u16* QH  = (u16*)(ws + 0x400000);      // [4800][512]    (0x4B0000)
    u16* KH  = (u16*)(ws + 0x900000);      // [32768][512]   (0x2000000) -> 0x2900000
    u16* CTX = (u16*)(ws + 0x2900000);     // [4800][256]    (0x258000)  -> 0x2B58000
    // after attn_b, KH region is dead -> reuse for post-attention buffers:
    u16* TGT2 = (u16*)(ws + 0x900000);     // [4800][256]
    u16* XBUF = (u16*)(ws + 0xB60000);     // [4800][256]
    u16* FFNB = (u16*)(ws + 0xDC0000);     // [4800][256]
    u16* HBUF = (u16*)(ws + 0x1020000);    // [4800][2048]   -> 0x22E0000

    float* out0 = (float*)d_out;
    float* out1 = out0 + 1228800;
    // VHT [16][8][32][2048] bf16 (16 MB) lives in out1's region (39.3 MB f32):
    // written by V-GEMM (mode 2), consumed by attn_a, then attn_b overwrites
    // all of out1 with attn_avg. Stream-ordered, out1 fully rewritten every call.
    u16* VHT = (u16*)out1;

    fold_q<<<192, 256, 0, stream>>>(w_qc, w_qp, w_qs, wq, WQ3T);
    fold_k<<<128, 256, 0, stream>>>(w_kc, w_kp, wk, WK2T);
    fold_v<<<32, 256, 0, stream>>>(w_v, wv_w, WV2T);
    fold_bias<<<5, 256, 0, stream>>>(b_qc, b_qp, b_qs, wq, bq, b_kc, b_kp, wk, bk,
                                     b_v, wv_w, bv, BQF, BKF, BVF);
    transpose_f2b<<<dim3(8, 8), 256, 0, stream>>>(wo, WOT, 256, 256);
    transpose_f2b<<<dim3(64, 8), 256, 0, stream>>>(w1, W1T, 256, 2048);
    transpose_f2b<<<dim3(8, 64), 256, 0, stream>>>(w2, W2T, 2048, 256);

    gemm_bt<<<dim3(38, 4), 256, 0, stream>>>(tgt, qpos, qsine, 256, 1, WQ3T, BQF, QH, 4800, 512, 768, 0);
    gemm_bt<<<dim3(256, 4), 256, 0, stream>>>(mem, pos, nullptr, 256, 1, WK2T, BKF, KH, 32768, 512, 512, 0);
    gemm_bt<<<dim3(256, 2), 256, 0, stream>>>(mem, nullptr, nullptr, 256, 1, WV2T, BVF, VHT, 32768, 256, 256, 2);

    attn_a<<<dim3(5, 8, 16), 256, 0, stream>>>(QH, KH, VHT, CTX, Z8);
    attn_b<<<dim3(16, 5, 16), 256, 0, stream>>>(QH, KH, Z8, out1);

    gemm_bt<<<dim3(38, 2), 256, 0, stream>>>(CTX, nullptr, nullptr, 256, 0, WOT, bo, TGT2, 4800, 256, 256, 0);
    ln_kernel<<<4800, 256, 0, stream>>>(tgt, 1, TGT2, g2, be2, XBUF, 0);
    gemm_bt<<<dim3(38, 16), 256, 0, stream>>>(XBUF, nullptr, nullptr, 256, 0, W1T, b1, HBUF, 4800, 2048, 256, 1);
    gemm_bt<<<dim3(38, 2), 256, 0, stream>>>(HBUF, nullptr, nullptr, 2048, 0, W2T, b2, FFNB, 4800, 256, 2048, 0);
    ln_kernel<<<4800, 256, 0, stream>>>(XBUF, 0, FFNB, g3, be3, out0, 1);
}

// Round 4
// 764.953 us; speedup vs baseline: 1.1691x; 1.1691x over previous
//
#include <hip/hip_runtime.h>

typedef unsigned short u16;
typedef __attribute__((ext_vector_type(8))) short short8;
typedef __attribute__((ext_vector_type(4))) float f32x4;

#define MFMA16(a, b, c) __builtin_amdgcn_mfma_f32_16x16x32_bf16(a, b, c, 0, 0, 0)

__device__ __forceinline__ float bf2f(u16 u) {
    return __uint_as_float(((unsigned)u) << 16);
}
__device__ __forceinline__ u16 f2bf(float f) {
    unsigned u = __float_as_uint(f);
    u += 0x7fff + ((u >> 16) & 1);
    return (u16)(u >> 16);
}

// ---------------------------------------------------------------------------
// Fold kernels v2: collapse (proj -> concat -> proj) into bf16 weights stored
// TRANSPOSED ([N][K]). Parallelization: o (output row of the folded W^T)
// across lanes -> wq/wk/wv column reads coalesced; source 64x64 tile staged
// in LDS, consumed as wave-uniform b128 broadcasts (conflict-free).
// Head-concat col map: mapC(c)=(c>>5)*64+(c&31), mapS=mapC+32.
// ---------------------------------------------------------------------------
#define FPAD 68

// WQ3T[512][768]: k<256: w_qc@wqC ; 256..511: w_qp@wqC ; 512..767: w_qs@wqS (x 1/8)
__global__ __launch_bounds__(256) void fold_q(const float* __restrict__ w_qc,
                                              const float* __restrict__ w_qp,
                                              const float* __restrict__ w_qs,
                                              const float* __restrict__ wq,
                                              u16* __restrict__ WQ3T) {
    __shared__ float Ws[64 * FPAD];
    int tid = threadIdx.x, lane = tid & 63, wave = tid >> 6;
    int o0 = blockIdx.x * 64, k0 = blockIdx.y * 64; // grid (8,12)
    int seg = k0 >> 8, kb = k0 & 255;
    int sOff = (seg == 2) ? 32 : 0;
    const float* wsrc = (seg == 0) ? w_qc : ((seg == 1) ? w_qp : w_qs);
    const float* wcol = wq + o0 + lane;
    float acc[16] = {};
    for (int cc = 0; cc < 256; cc += 64) {
#pragma unroll
        for (int i = 0; i < 4; i++) {
            int idx = tid * 4 + i;
            int row = idx >> 4, c4 = (idx & 15) * 4;
            *(float4*)(&Ws[row * FPAD + c4]) =
                *(const float4*)(wsrc + (size_t)(kb + row) * 256 + cc + c4);
        }
        __syncthreads();
        for (int c4 = 0; c4 < 64; c4 += 4) {
            float wv[4];
#pragma unroll
            for (int e = 0; e < 4; e++) {
                int c = cc + c4 + e;
                int mc = (c >> 5) * 64 + (c & 31) + sOff;
                wv[e] = wcol[(size_t)mc * 512];
            }
            const float* wsp = &Ws[wave * 16 * FPAD + c4];
#pragma unroll
            for (int j = 0; j < 16; j++) {
                float4 wj = *(const float4*)(wsp + j * FPAD);
                acc[j] += wj.x * wv[0] + wj.y * wv[1] + wj.z * wv[2] + wj.w * wv[3];
            }
        }
        __syncthreads();
    }
    u16 outv[16];
#pragma unroll
    for (int j = 0; j < 16; j++) outv[j] = f2bf(acc[j] * 0.125f);
    u16* op = WQ3T + (size_t)(o0 + lane) * 768 + k0 + wave * 16;
    *(uint4*)op = *(uint4*)outv;
    *(uint4*)(op + 8) = *((uint4*)outv + 1);
}

// WK2T[512][512]: k<256: w_kc@wkC ; k>=256: w_kp@(wkC+wkS)
__global__ __launch_bounds__(256) void fold_k(const float* __restrict__ w_kc,
                                              const float* __restrict__ w_kp,
                                              const float* __restrict__ wk,
                                              u16* __restrict__ WK2T) {
    __shared__ float Ws[64 * FPAD];
    int tid = threadIdx.x, lane = tid & 63, wave = tid >> 6;
    int o0 = blockIdx.x * 64, k0 = blockIdx.y * 64; // grid (8,8)
    bool second = k0 >= 256;
    const float* wsrc = second ? w_kp : w_kc;
    int kb = second ? k0 - 256 : k0;
    const float* wcol = wk + o0 + lane;
    float acc[16] = {};
    for (int cc = 0; cc < 256; cc += 64) {
#pragma unroll
        for (int i = 0; i < 4; i++) {
            int idx = tid * 4 + i;
            int row = idx >> 4, c4 = (idx & 15) * 4;
            *(float4*)(&Ws[row * FPAD + c4]) =
                *(const float4*)(wsrc + (size_t)(kb + row) * 256 + cc + c4);
        }
        __syncthreads();
        for (int c4 = 0; c4 < 64; c4 += 4) {
            float wv[4];
#pragma unroll
            for (int e = 0; e < 4; e++) {
                int c = cc + c4 + e;
                int mc = (c >> 5) * 64 + (c & 31);
                float w0 = wcol[(size_t)mc * 512];
                if (second) w0 += wcol[(size_t)(mc + 32) * 512];
                wv[e] = w0;
            }
            const float* wsp = &Ws[wave * 16 * FPAD + c4];
#pragma unroll
            for (int j = 0; j < 16; j++) {
                float4 wj = *(const float4*)(wsp + j * FPAD);
                acc[j] += wj.x * wv[0] + wj.y * wv[1] + wj.z * wv[2] + wj.w * wv[3];
            }
        }
        __syncthreads();
    }
    u16 outv[16];
#pragma unroll
    for (int j = 0; j < 16; j++) outv[j] = f2bf(acc[j]);
    u16* op = WK2T + (size_t)(o0 + lane) * 512 + k0 + wave * 16;
    *(uint4*)op = *(uint4*)outv;
    *(uint4*)(op + 8) = *((uint4*)outv + 1);
}

// WV2T[256][256] = (w_v @ wv)^T
__global__ __launch_bounds__(256) void fold_v(const float* __restrict__ w_v,
                                              const float* __restrict__ wv_w,
                                              u16* __restrict__ WV2T) {
    __shared__ float Ws[64 * FPAD];
    int tid = threadIdx.x, lane = tid & 63, wave = tid >> 6;
    int o0 = blockIdx.x * 64, k0 = blockIdx.y * 64; // grid (4,4)
    const float* wcol = wv_w + o0 + lane;
    float acc[16] = {};
    for (int cc = 0; cc < 256; cc += 64) {
#pragma unroll
        for (int i = 0; i < 4; i++) {
            int idx = tid * 4 + i;
            int row = idx >> 4, c4 = (idx & 15) * 4;
            *(float4*)(&Ws[row * FPAD + c4]) =
                *(const float4*)(w_v + (size_t)(k0 + row) * 256 + cc + c4);
        }
        __syncthreads();
        for (int c4 = 0; c4 < 64; c4 += 4) {
            float wv[4];
#pragma unroll
            for (int e = 0; e < 4; e++) wv[e] = wcol[(size_t)(cc + c4 + e) * 256];
            const float* wsp = &Ws[wave * 16 * FPAD + c4];
#pragma unroll
            for (int j = 0; j < 16; j++) {
                float4 wj = *(const float4*)(wsp + j * FPAD);
                acc[j] += wj.x * wv[0] + wj.y * wv[1] + wj.z * wv[2] + wj.w * wv[3];
            }
        }
        __syncthreads();
    }
    u16 outv[16];
#pragma unroll
    for (int j = 0; j < 16; j++) outv[j] = f2bf(acc[j]);
    u16* op = WV2T + (size_t)(o0 + lane) * 256 + k0 + wave * 16;
    *(uint4*)op = *(uint4*)outv;
    *(uint4*)(op + 8) = *((uint4*)outv + 1);
}

// folded biases (f32): BQF[512], BKF[512], BVF[256]. grid 20 blocks:
// 0..7 -> BQ (64 o each), 8..15 -> BK, 16..19 -> BV. o across lanes
// (coalesced weight-column reads), c split over 4 waves, LDS reduce.
__global__ __launch_bounds__(256) void fold_bias(
    const float* b_qc, const float* b_qp, const float* b_qs, const float* wq, const float* bq,
    const float* b_kc, const float* b_kp, const float* wk, const float* bk,
    const float* b_v, const float* wv_w, const float* bv,
    float* BQF, float* BKF, float* BVF) {
    __shared__ float red[4][64];
    int tid = threadIdx.x, lane = tid & 63, wave = tid >> 6;
    int blk = blockIdx.x;
    float acc = 0.f;
    if (blk < 8) {
        int o = blk * 64 + lane;
        for (int c = wave * 64; c < wave * 64 + 64; c++) {
            int mc = (c >> 5) * 64 + (c & 31);
            acc += (b_qc[c] + b_qp[c]) * wq[(size_t)mc * 512 + o];
            acc += b_qs[c] * wq[(size_t)(mc + 32) * 512 + o];
        }
        red[wave][lane] = acc;
        __syncthreads();
        if (wave == 0)
            BQF[o] = (bq[o] + red[0][lane] + red[1][lane] + red[2][lane] + red[3][lane]) * 0.125f;
    } else if (blk < 16) {
        int o = (blk - 8) * 64 + lane;
        for (int c = wave * 64; c < wave * 64 + 64; c++) {
            int mc = (c >> 5) * 64 + (c & 31);
            acc += (b_kc[c] + b_kp[c]) * wk[(size_t)mc * 512 + o];
            acc += b_kp[c] * wk[(size_t)(mc + 32) * 512 + o];
        }
        red[wave][lane] = acc;
        __syncthreads();
        if (wave == 0)
            BKF[o] = bk[o] + red[0][lane] + red[1][lane] + red[2][lane] + red[3][lane];
    } else {
        int o = (blk - 16) * 64 + lane;
        for (int c = wave * 64; c < wave * 64 + 64; c++)
            acc += b_v[c] * wv_w[(size_t)c * 256 + o];
        red[wave][lane] = acc;
        __syncthreads();
        if (wave == 0)
            BVF[o] = bv[o] + red[0][lane] + red[1][lane] + red[2][lane] + red[3][lane];
    }
}

// f32 -> bf16 transpose: dst[C][R] = src[R][C], 32x32 tiles
__global__ __launch_bounds__(256) void transpose_f2b(const float* __restrict__ src,
                                                     u16* __restrict__ dst, int R, int C) {
    __shared__ float tile[32][33];
    int c0 = blockIdx.x * 32, r0 = blockIdx.y * 32;
    int t = threadIdx.x;
    int j = t & 31, i0 = (t >> 5) * 4;
#pragma unroll
    for (int ii = 0; ii < 4; ii++)
        tile[i0 + ii][j] = src[(size_t)(r0 + i0 + ii) * C + c0 + j];
    __syncthreads();
    int i2 = t & 31, j0 = (t >> 5) * 4;
#pragma unroll
    for (int jj = 0; jj < 4; jj++)
        dst[(size_t)(c0 + j0 + jj) * R + r0 + i2] = f2bf(tile[i2][j0 + jj]);
}

// ---------------------------------------------------------------------------
// Main GEMM: C[M][N] = concat_parts(A)[M][K] @ BT[N][K]^T + bias.
// 128x128 tile, BK=32, 4 waves each 64x64 (4x4 mfma 16x16x32).
// A: f32 (a_f32=1) or bf16; staged to bf16 LDS. BT: bf16 (preprocessed).
// When astride==256, part p=k0>>8 selects A0/A1/A2 (row stride 256); else A0.
// mode: 0 = bf16 store C[M][N]; 1 = relu+bf16 store; 2 = scatter bf16 into
// V-transpose layout vhT[b][h][d][k] (row=k*16+b, col=h*32+d).
// ---------------------------------------------------------------------------
#define APAD 40
__global__ __launch_bounds__(256) void gemm_bt(
    const void* __restrict__ A0v, const void* __restrict__ A1v, const void* __restrict__ A2v,
    int astride, int a_f32, const u16* __restrict__ BT, const float* __restrict__ bias,
    u16* __restrict__ C, int M, int N, int K, int mode) {
    __shared__ u16 As[128 * APAD];
    __shared__ u16 Bs[128 * APAD];
    int tid = threadIdx.x;
    int wave = tid >> 6, lane = tid & 63;
    int l15 = lane & 15, quad = lane >> 4;
    int wm = (wave >> 1) * 64, wn = (wave & 1) * 64;
    int gm0 = blockIdx.x * 128, gn0 = blockIdx.y * 128;
    f32x4 acc[4][4] = {};
    for (int k0 = 0; k0 < K; k0 += 32) {
        const void* ap;
        int kin;
        if (astride == 256) {
            int p = k0 >> 8;
            ap = (p == 0) ? A0v : ((p == 1) ? A1v : A2v);
            kin = k0 & 255;
        } else {
            ap = A0v;
            kin = k0;
        }
#pragma unroll
        for (int i = 0; i < 2; i++) {
            int idx = tid * 2 + i;
            int row = idx >> 2, seg = (idx & 3) * 8;
            int grow = gm0 + row;
            u16 tmp[8];
            if (a_f32) {
                float vv[8] = {0.f, 0.f, 0.f, 0.f, 0.f, 0.f, 0.f, 0.f};
                if (grow < M) {
                    const float* apf = (const float*)ap;
                    float4 u0 = *(const float4*)(apf + (size_t)grow * astride + kin + seg);
                    float4 u1 = *(const float4*)(apf + (size_t)grow * astride + kin + seg + 4);
                    vv[0] = u0.x; vv[1] = u0.y; vv[2] = u0.z; vv[3] = u0.w;
                    vv[4] = u1.x; vv[5] = u1.y; vv[6] = u1.z; vv[7] = u1.w;
                }
#pragma unroll
                for (int e = 0; e < 8; e++) tmp[e] = f2bf(vv[e]);
            } else {
                uint4 v;
                v.x = v.y = v.z = v.w = 0;
                if (grow < M) v = *(const uint4*)((const u16*)ap + (size_t)grow * astride + kin + seg);
                *(uint4*)tmp = v;
            }
            *(uint4*)(&As[row * APAD + seg]) = *(uint4*)tmp;
            int nrow = gn0 + row;
            uint4 w = *(const uint4*)(BT + (size_t)nrow * K + k0 + seg);
            *(uint4*)(&Bs[row * APAD + seg]) = w;
        }
        __syncthreads();
        short8 afr[4], bfr[4];
#pragma unroll
        for (int i = 0; i < 4; i++)
            afr[i] = *(const short8*)(&As[(wm + i * 16 + l15) * APAD + quad * 8]);
#pragma unroll
        for (int j = 0; j < 4; j++)
            bfr[j] = *(const short8*)(&Bs[(wn + j * 16 + l15) * APAD + quad * 8]);
#pragma unroll
        for (int i = 0; i < 4; i++)
#pragma unroll
            for (int j = 0; j < 4; j++) acc[i][j] = MFMA16(afr[i], bfr[j], acc[i][j]);
        __syncthreads();
    }
#pragma unroll
    for (int i = 0; i < 4; i++) {
        int row = gm0 + wm + i * 16 + quad * 4;
#pragma unroll
        for (int j = 0; j < 4; j++) {
            int col = gn0 + wn + j * 16 + l15;
            float bvv = bias[col];
#pragma unroll
            for (int r = 0; r < 4; r++) {
                int grow = row + r;
                if (grow < M) {
                    float v = acc[i][j][r] + bvv;
                    if (mode == 1) v = fmaxf(v, 0.f);
                    if (mode == 2) {
                        int kk = grow >> 4, bb = grow & 15;
                        int hh = col >> 5, dd = col & 31;
                        C[(((size_t)bb * 8 + hh) * 32 + dd) * 2048 + kk] = f2bf(v);
                    } else {
                        C[(size_t)grow * N + col] = f2bf(v);
                    }
                }
            }
        }
    }
}

// ---------------------------------------------------------------------------
// Attention kernel A: per (qtile, h, b) — one pass over k: unnormalized
// exp-sum Z and unnormalized ctx (logits tiny -> no max subtraction needed);
// normalize in epilogue, store ctx (bf16) and 1/(8Z) (f32).
// ---------------------------------------------------------------------------
__global__ __launch_bounds__(256) void attn_a(const u16* __restrict__ qh,
                                              const u16* __restrict__ kh,
                                              const u16* __restrict__ vhT,
                                              u16* __restrict__ ctxbuf,
                                              float* __restrict__ z8inv) {
    int qt = blockIdx.x, h = blockIdx.y, b = blockIdx.z;
    __shared__ u16 Qt[64 * 72];
    __shared__ u16 Kc[128 * 72];
    __shared__ u16 Pt[64 * 136];
    __shared__ u16 VTc[32 * 136];
    int tid = threadIdx.x, wave = tid >> 6, lane = tid & 63;
    int l15 = lane & 15, quad = lane >> 4;
    int q0 = qt * 64;
#pragma unroll
    for (int i = 0; i < 2; i++) {
        int idx = tid * 2 + i;
        int row = idx >> 3, seg = (idx & 7) * 8;
        uint4 v;
        v.x = v.y = v.z = v.w = 0;
        int q = q0 + row;
        if (q < 300) v = *(const uint4*)(qh + ((size_t)q * 16 + b) * 512 + h * 64 + seg);
        *(uint4*)(&Qt[row * 72 + seg]) = v;
    }
    const f32x4 zf = {0.f, 0.f, 0.f, 0.f};
    f32x4 cacc[2] = {};
    float zrow[4] = {0.f, 0.f, 0.f, 0.f};
    for (int kc0 = 0; kc0 < 2048; kc0 += 128) {
#pragma unroll
        for (int i = 0; i < 4; i++) {
            int idx = tid * 4 + i;
            int row = idx >> 3, seg = (idx & 7) * 8;
            *(uint4*)(&Kc[row * 72 + seg]) =
                *(const uint4*)(kh + ((size_t)(kc0 + row) * 16 + b) * 512 + h * 64 + seg);
        }
#pragma unroll
        for (int i = 0; i < 2; i++) {
            int idx = tid * 2 + i;
            int row = idx >> 4, seg = (idx & 15) * 8;
            *(uint4*)(&VTc[row * 136 + seg]) =
                *(const uint4*)(vhT + (((size_t)b * 8 + h) * 32 + row) * 2048 + kc0 + seg);
        }
        __syncthreads();
        f32x4 sacc[8];
#pragma unroll
        for (int t = 0; t < 8; t++) sacc[t] = zf;
#pragma unroll
        for (int d0 = 0; d0 < 64; d0 += 32) {
            short8 af = *(const short8*)(&Qt[(wave * 16 + l15) * 72 + d0 + quad * 8]);
#pragma unroll
            for (int t = 0; t < 8; t++) {
                short8 bf = *(const short8*)(&Kc[(t * 16 + l15) * 72 + d0 + quad * 8]);
                sacc[t] = MFMA16(af, bf, sacc[t]);
            }
        }
#pragma unroll
        for (int t = 0; t < 8; t++) {
#pragma unroll
            for (int r = 0; r < 4; r++) {
                float p = __expf(sacc[t][r]);
                zrow[r] += p;
                Pt[(wave * 16 + quad * 4 + r) * 136 + t * 16 + l15] = f2bf(p);
            }
        }
#pragma unroll
        for (int kk0 = 0; kk0 < 128; kk0 += 32) {
            short8 af = *(const short8*)(&Pt[(wave * 16 + l15) * 136 + kk0 + quad * 8]);
#pragma unroll
            for (int t = 0; t < 2; t++) {
                short8 bf = *(const short8*)(&VTc[(t * 16 + l15) * 136 + kk0 + quad * 8]);
                cacc[t] = MFMA16(af, bf, cacc[t]);
            }
        }
        __syncthreads();
    }
#pragma unroll
    for (int r = 0; r < 4; r++) {
        float z = zrow[r];
        z += __shfl_xor(z, 1);
        z += __shfl_xor(z, 2);
        z += __shfl_xor(z, 4);
        z += __shfl_xor(z, 8);
        zrow[r] = z;
    }
#pragma unroll
    for (int r = 0; r < 4; r++) {
        int q = q0 + wave * 16 + quad * 4 + r;
        if (q < 300) {
            float rz = 1.0f / zrow[r];
#pragma unroll
            for (int t = 0; t < 2; t++)
                ctxbuf[((size_t)q * 16 + b) * 256 + h * 32 + t * 16 + l15] = f2bf(cacc[t][r] * rz);
            if (l15 == 0) z8inv[((size_t)b * 8 + h) * 320 + q] = rz * 0.125f;
        }
    }
}

// ---------------------------------------------------------------------------
// Attention kernel B: per (kchunk, qtile, b) — loop all 8 heads, recompute
// logits, p = exp(s) * (1/(8Z)), accumulate head-average, write attn_avg (f32).
// ---------------------------------------------------------------------------
__global__ __launch_bounds__(256) void attn_b(const u16* __restrict__ qh,
                                              const u16* __restrict__ kh,
                                              const float* __restrict__ z8inv,
                                              float* __restrict__ out1) {
    int kc0 = blockIdx.x * 128, qt = blockIdx.y, b = blockIdx.z;
    __shared__ u16 Qt[64 * 72];
    __shared__ u16 Kc[128 * 72];
    int tid = threadIdx.x, wave = tid >> 6, lane = tid & 63;
    int l15 = lane & 15, quad = lane >> 4;
    int q0 = qt * 64;
    const f32x4 zf = {0.f, 0.f, 0.f, 0.f};
    float avg[8][4] = {};
    for (int h = 0; h < 8; h++) {
#pragma unroll
        for (int i = 0; i < 2; i++) {
            int idx = tid * 2 + i;
            int row = idx >> 3, seg = (idx & 7) * 8;
            uint4 v;
            v.x = v.y = v.z = v.w = 0;
            int q = q0 + row;
            if (q < 300) v = *(const uint4*)(qh + ((size_t)q * 16 + b) * 512 + h * 64 + seg);
            *(uint4*)(&Qt[row * 72 + seg]) = v;
        }
#pragma unroll
        for (int i = 0; i < 4; i++) {
            int idx = tid * 4 + i;
            int row = idx >> 3, seg = (idx & 7) * 8;
            *(uint4*)(&Kc[row * 72 + seg]) =
                *(const uint4*)(kh + ((size_t)(kc0 + row) * 16 + b) * 512 + h * 64 + seg);
        }
        __syncthreads();
        f32x4 sacc[8];
#pragma unroll
        for (int t = 0; t < 8; t++) sacc[t] = zf;
#pragma unroll
        for (int d0 = 0; d0 < 64; d0 += 32) {
            short8 af = *(const short8*)(&Qt[(wave * 16 + l15) * 72 + d0 + quad * 8]);
#pragma unroll
            for (int t = 0; t < 8; t++) {
                short8 bf = *(const short8*)(&Kc[(t * 16 + l15) * 72 + d0 + quad * 8]);
                sacc[t] = MFMA16(af, bf, sacc[t]);
            }
        }
        float zi[4];
#pragma unroll
        for (int r = 0; r < 4; r++) {
            int q = q0 + wave * 16 + quad * 4 + r;
            zi[r] = z8inv[((size_t)b * 8 + h) * 320 + (q < 319 ? q : 319)];
        }
#pragma unroll
        for (int t = 0; t < 8; t++)
#pragma unroll
            for (int r = 0; r < 4; r++) avg[t][r] += __expf(sacc[t][r]) * zi[r];
        __syncthreads();
    }
#pragma unroll
    for (int r = 0; r < 4; r++) {
        int q = q0 + wave * 16 + quad * 4 + r;
        if (q < 300) {
#pragma unroll
            for (int t = 0; t < 8; t++)
                out1[((size_t)b * 300 + q) * 2048 + kc0 + t * 16 + l15] = avg[t][r];
        }
    }
}

// residual add + LayerNorm over last dim (256). a: f32 or bf16; out: f32 or bf16.
__global__ __launch_bounds__(256) void ln_kernel(const void* __restrict__ a, int a_f32,
                                                 const u16* __restrict__ bres,
                                                 const float* __restrict__ g,
                                                 const float* __restrict__ be,
                                                 void* __restrict__ out, int out_f32) {
    int row = blockIdx.x, t = threadIdx.x;
    float av = a_f32 ? ((const float*)a)[(size_t)row * 256 + t]
                     : bf2f(((const u16*)a)[(size_t)row * 256 + t]);
    float v = av + bf2f(bres[(size_t)row * 256 + t]);
    float s = v, sq = v * v;
#pragma unroll
    for (int o = 32; o; o >>= 1) {
        s += __shfl_xor(s, o);
        sq += __shfl_xor(sq, o);
    }
    __shared__ float red[8];
    int wave = t >> 6, lane = t & 63;
    if (lane == 0) {
        red[wave] = s;
        red[4 + wave] = sq;
    }
    __syncthreads();
    s = red[0] + red[1] + red[2] + red[3];
    sq = red[4] + red[5] + red[6] + red[7];
    float mean = s * (1.f / 256.f);
    float var = sq * (1.f / 256.f) - mean * mean;
    float rs = rsqrtf(var + 1e-5f);
    float res = (v - mean) * rs * g[t] + be[t];
    if (out_f32) ((float*)out)[(size_t)row * 256 + t] = res;
    else ((u16*)out)[(size_t)row * 256 + t] = f2bf(res);
}

// ---------------------------------------------------------------------------
extern "C" void kernel_launch(void* const* d_in, const int* in_sizes, int n_in,
                              void* d_out, int out_size, void* d_ws, size_t ws_size,
                              hipStream_t stream) {
    (void)in_sizes; (void)n_in; (void)out_size; (void)ws_size;
    const float* tgt = (const float*)d_in[0];
    const float* mem = (const float*)d_in[1];
    const float* pos = (const float*)d_in[2];
    const float* qpos = (const float*)d_in[3];
    const float* qsine = (const float*)d_in[4];
    const float* w_qc = (const float*)d_in[5];
    const float* b_qc = (const float*)d_in[6];
    const float* w_qp = (const float*)d_in[7];
    const float* b_qp = (const float*)d_in[8];
    const float* w_kc = (const float*)d_in[9];
    const float* b_kc = (const float*)d_in[10];
    const float* w_kp = (const float*)d_in[11];
    const float* b_kp = (const float*)d_in[12];
    const float* w_v = (const float*)d_in[13];
    const float* b_v = (const float*)d_in[14];
    const float* w_qs = (const float*)d_in[15];
    const float* b_qs = (const float*)d_in[16];
    const float* wq = (const float*)d_in[17];
    const float* bq = (const float*)d_in[18];
    const float* wk = (const float*)d_in[19];
    const float* bk = (const float*)d_in[20];
    const float* wv_w = (const float*)d_in[21];
    const float* bv = (const float*)d_in[22];
    const float* wo = (const float*)d_in[23];
    const float* bo = (const float*)d_in[24];
    const float* w1 = (const float*)d_in[25];
    const float* b1 = (const float*)d_in[26];
    const float* w2 = (const float*)d_in[27];
    const float* b2 = (const float*)d_in[28];
    const float* g2 = (const float*)d_in[29];
    const float* be2 = (const float*)d_in[30];
    const float* g3 = (const float*)d_in[31];
    const float* be3 = (const float*)d_in[32];

    // --- workspace layout (peak 0x2B58000 = 45.6 MB) ---
    char* ws = (char*)d_ws;
    u16* WQ3T = (u16*)(ws + 0x000000);     // 512x768 bf16   (0xC0000)
    u16* WK2T = (u16*)(ws + 0x0C0000);     // 512x512        (0x80000)
    u16* WV2T = (u16*)(ws + 0x140000);     // 256x256        (0x20000)
    u16* WOT  = (u16*)(ws + 0x160000);     // 256x256        (0x20000)
    u16* W1T  = (u16*)(ws + 0x180000);     // 2048x256       (0x100000)
    u16* W2T  = (u16*)(ws + 0x280000);     // 256x2048       (0x100000)
    float* BQF = (float*)(ws + 0x380000);
    float* BKF = (float*)(ws + 0x381000);
    float* BVF = (float*)(ws + 0x382000);
    float* Z8  = (float*)(ws + 0x390000);  // 16x8x320 f32   (0x28000)
    u16* QH  = (u16*)(ws + 0x400000);      // [4800][512]    (0x4B0000)
    u16* KH  = (u16*)(ws + 0x900000);      // [32768][512]   (0x2000000) -> 0x2900000
    u16* CTX = (u16*)(ws + 0x2900000);     // [4800][256]    (0x258000)  -> 0x2B58000
    // after attn_b, KH region is dead -> reuse for post-attention buffers:
    u16* TGT2 = (u16*)(ws + 0x900000);     // [4800][256]
    u16* XBUF = (u16*)(ws + 0xB60000);     // [4800][256]
    u16* FFNB = (u16*)(ws + 0xDC0000);     // [4800][256]
    u16* HBUF = (u16*)(ws + 0x1020000);    // [4800][2048]   -> 0x22E0000

    float* out0 = (float*)d_out;
    float* out1 = out0 + 1228800;
    // VHT [16][8][32][2048] bf16 (16 MB) lives in out1's region (39.3 MB f32):
    // written by V-GEMM (mode 2), consumed by attn_a, then attn_b overwrites
    // all of out1 with attn_avg. Stream-ordered, out1 fully rewritten every call.
    u16* VHT = (u16*)out1;

    fold_q<<<dim3(8, 12), 256, 0, stream>>>(w_qc, w_qp, w_qs, wq, WQ3T);
    fold_k<<<dim3(8, 8), 256, 0, stream>>>(w_kc, w_kp, wk, WK2T);
    fold_v<<<dim3(4, 4), 256, 0, stream>>>(w_v, wv_w, WV2T);
    fold_bias<<<20, 256, 0, stream>>>(b_qc, b_qp, b_qs, wq, bq, b_kc, b_kp, wk, bk,
                                      b_v, wv_w, bv, BQF, BKF, BVF);
    transpose_f2b<<<dim3(8, 8), 256, 0, stream>>>(wo, WOT, 256, 256);
    transpose_f2b<<<dim3(64, 8), 256, 0, stream>>>(w1, W1T, 256, 2048);
    transpose_f2b<<<dim3(8, 64), 256, 0, stream>>>(w2, W2T, 2048, 256);

    gemm_bt<<<dim3(38, 4), 256, 0, stream>>>(tgt, qpos, qsine, 256, 1, WQ3T, BQF, QH, 4800, 512, 768, 0);
    gemm_bt<<<dim3(256, 4), 256, 0, stream>>>(mem, pos, nullptr, 256, 1, WK2T, BKF, KH, 32768, 512, 512, 0);
    gemm_bt<<<dim3(256, 2), 256, 0, stream>>>(mem, nullptr, nullptr, 256, 1, WV2T, BVF, VHT, 32768, 256, 256, 2);

    attn_a<<<dim3(5, 8, 16), 256, 0, stream>>>(QH, KH, VHT, CTX, Z8);
    attn_b<<<dim3(16, 5, 16), 256, 0, stream>>>(QH, KH, Z8, out1);

    gemm_bt<<<dim3(38, 2), 256, 0, stream>>>(CTX, nullptr, nullptr, 256, 0, WOT, bo, TGT2, 4800, 256, 256, 0);
    ln_kernel<<<4800, 256, 0, stream>>>(tgt, 1, TGT2, g2, be2, XBUF, 0);
    gemm_bt<<<dim3(38, 16), 256, 0, stream>>>(XBUF, nullptr, nullptr, 256, 0, W1T, b1, HBUF, 4800, 2048, 256, 1);
    gemm_bt<<<dim3(38, 2), 256, 0, stream>>>(HBUF, nullptr, nullptr, 2048, 0, W2T, b2, FFNB, 4800, 256, 2048, 0);
    ln_kernel<<<4800, 256, 0, stream>>>(XBUF, 0, FFNB, g3, be3, out0, 1);
}

// Round 5
// 654.127 us; speedup vs baseline: 1.3671x; 1.1694x over previous
//
#include <hip/hip_runtime.h>

typedef unsigned short u16;
typedef __attribute__((ext_vector_type(8))) short short8;
typedef __attribute__((ext_vector_type(4))) float f32x4;

#define MFMA16(a, b, c) __builtin_amdgcn_mfma_f32_16x16x32_bf16(a, b, c, 0, 0, 0)

__device__ __forceinline__ float bf2f(u16 u) {
    return __uint_as_float(((unsigned)u) << 16);
}
__device__ __forceinline__ u16 f2bf(float f) {
    unsigned u = __float_as_uint(f);
    u += 0x7fff + ((u >> 16) & 1);
    return (u16)(u >> 16);
}

// ---------------------------------------------------------------------------
// Fold kernels v3: collapse (proj -> concat -> proj) into bf16 weights stored
// TRANSPOSED ([N][K]). One thread per o (lane-coalesced wq/wk/wv column
// reads), 4 k-outputs per thread (each loaded w0 reused x4); wsrc[k][c] is
// block-uniform -> scalar loads. No LDS. c-loop unrolled for VMEM ILP.
// Head-concat col map: mapC(c)=(c>>5)*64+(c&31), mapS=mapC+32.
// ---------------------------------------------------------------------------

// WQ3T[512][768]: k<256: w_qc@wqC ; 256..511: w_qp@wqC ; 512..767: w_qs@wqS (x 1/8)
// grid (2, 192), block 256: o = bx*256+tid, k0 = by*4
__global__ __launch_bounds__(256) void fold_q(const float* __restrict__ w_qc,
                                              const float* __restrict__ w_qp,
                                              const float* __restrict__ w_qs,
                                              const float* __restrict__ wq,
                                              u16* __restrict__ WQ3T) {
    int o = blockIdx.x * 256 + threadIdx.x;
    int k0 = blockIdx.y * 4;
    int seg = k0 >> 8, kb = k0 & 255;
    const float* wsrc = (seg == 0) ? w_qc : ((seg == 1) ? w_qp : w_qs);
    int sOff = (seg == 2) ? 32 : 0;
    const float* wcol = wq + o;
    float acc[4] = {0.f, 0.f, 0.f, 0.f};
#pragma unroll 8
    for (int c = 0; c < 256; c++) {
        int mc = (c >> 5) * 64 + (c & 31) + sOff;
        float w0 = wcol[(size_t)mc * 512];
#pragma unroll
        for (int j = 0; j < 4; j++)
            acc[j] += wsrc[(size_t)(kb + j) * 256 + c] * w0;
    }
    u16 outv[4];
#pragma unroll
    for (int j = 0; j < 4; j++) outv[j] = f2bf(acc[j] * 0.125f);
    *(uint2*)(WQ3T + (size_t)o * 768 + k0) = *(uint2*)outv;
}

// WK2T[512][512]: k<256: w_kc@wkC ; k>=256: w_kp@(wkC+wkS)
// grid (2, 128), block 256
__global__ __launch_bounds__(256) void fold_k(const float* __restrict__ w_kc,
                                              const float* __restrict__ w_kp,
                                              const float* __restrict__ wk,
                                              u16* __restrict__ WK2T) {
    int o = blockIdx.x * 256 + threadIdx.x;
    int k0 = blockIdx.y * 4;
    bool second = k0 >= 256;
    int kb = second ? k0 - 256 : k0;
    const float* wcol = wk + o;
    float acc[4] = {0.f, 0.f, 0.f, 0.f};
    if (second) {
#pragma unroll 8
        for (int c = 0; c < 256; c++) {
            int mc = (c >> 5) * 64 + (c & 31);
            float w0 = wcol[(size_t)mc * 512] + wcol[(size_t)(mc + 32) * 512];
#pragma unroll
            for (int j = 0; j < 4; j++)
                acc[j] += w_kp[(size_t)(kb + j) * 256 + c] * w0;
        }
    } else {
#pragma unroll 8
        for (int c = 0; c < 256; c++) {
            int mc = (c >> 5) * 64 + (c & 31);
            float w0 = wcol[(size_t)mc * 512];
#pragma unroll
            for (int j = 0; j < 4; j++)
                acc[j] += w_kc[(size_t)(kb + j) * 256 + c] * w0;
        }
    }
    u16 outv[4];
#pragma unroll
    for (int j = 0; j < 4; j++) outv[j] = f2bf(acc[j]);
    *(uint2*)(WK2T + (size_t)o * 512 + k0) = *(uint2*)outv;
}

// WV2T[256][256] = (w_v @ wv)^T ; grid (1, 64), block 256
__global__ __launch_bounds__(256) void fold_v(const float* __restrict__ w_v,
                                              const float* __restrict__ wv_w,
                                              u16* __restrict__ WV2T) {
    int o = threadIdx.x;
    int k0 = blockIdx.y * 4;
    float acc[4] = {0.f, 0.f, 0.f, 0.f};
#pragma unroll 8
    for (int c = 0; c < 256; c++) {
        float w0 = wv_w[(size_t)c * 256 + o];
#pragma unroll
        for (int j = 0; j < 4; j++)
            acc[j] += w_v[(size_t)(k0 + j) * 256 + c] * w0;
    }
    u16 outv[4];
#pragma unroll
    for (int j = 0; j < 4; j++) outv[j] = f2bf(acc[j]);
    *(uint2*)(WV2T + (size_t)o * 256 + k0) = *(uint2*)outv;
}

// folded biases (f32): BQF[512], BKF[512], BVF[256]. grid 20 blocks:
// 0..7 -> BQ (64 o each), 8..15 -> BK, 16..19 -> BV. o across lanes
// (coalesced weight-column reads), c split over 4 waves, LDS reduce.
__global__ __launch_bounds__(256) void fold_bias(
    const float* b_qc, const float* b_qp, const float* b_qs, const float* wq, const float* bq,
    const float* b_kc, const float* b_kp, const float* wk, const float* bk,
    const float* b_v, const float* wv_w, const float* bv,
    float* BQF, float* BKF, float* BVF) {
    __shared__ float red[4][64];
    int tid = threadIdx.x, lane = tid & 63, wave = tid >> 6;
    int blk = blockIdx.x;
    float acc = 0.f;
    if (blk < 8) {
        int o = blk * 64 + lane;
#pragma unroll 4
        for (int c = wave * 64; c < wave * 64 + 64; c++) {
            int mc = (c >> 5) * 64 + (c & 31);
            acc += (b_qc[c] + b_qp[c]) * wq[(size_t)mc * 512 + o];
            acc += b_qs[c] * wq[(size_t)(mc + 32) * 512 + o];
        }
        red[wave][lane] = acc;
        __syncthreads();
        if (wave == 0)
            BQF[o] = (bq[o] + red[0][lane] + red[1][lane] + red[2][lane] + red[3][lane]) * 0.125f;
    } else if (blk < 16) {
        int o = (blk - 8) * 64 + lane;
#pragma unroll 4
        for (int c = wave * 64; c < wave * 64 + 64; c++) {
            int mc = (c >> 5) * 64 + (c & 31);
            acc += (b_kc[c] + b_kp[c]) * wk[(size_t)mc * 512 + o];
            acc += b_kp[c] * wk[(size_t)(mc + 32) * 512 + o];
        }
        red[wave][lane] = acc;
        __syncthreads();
        if (wave == 0)
            BKF[o] = bk[o] + red[0][lane] + red[1][lane] + red[2][lane] + red[3][lane];
    } else {
        int o = (blk - 16) * 64 + lane;
#pragma unroll 4
        for (int c = wave * 64; c < wave * 64 + 64; c++)
            acc += b_v[c] * wv_w[(size_t)c * 256 + o];
        red[wave][lane] = acc;
        __syncthreads();
        if (wave == 0)
            BVF[o] = bv[o] + red[0][lane] + red[1][lane] + red[2][lane] + red[3][lane];
    }
}

// f32 -> bf16 transpose: dst[C][R] = src[R][C], 32x32 tiles
__global__ __launch_bounds__(256) void transpose_f2b(const float* __restrict__ src,
                                                     u16* __restrict__ dst, int R, int C) {
    __shared__ float tile[32][33];
    int c0 = blockIdx.x * 32, r0 = blockIdx.y * 32;
    int t = threadIdx.x;
    int j = t & 31, i0 = (t >> 5) * 4;
#pragma unroll
    for (int ii = 0; ii < 4; ii++)
        tile[i0 + ii][j] = src[(size_t)(r0 + i0 + ii) * C + c0 + j];
    __syncthreads();
    int i2 = t & 31, j0 = (t >> 5) * 4;
#pragma unroll
    for (int jj = 0; jj < 4; jj++)
        dst[(size_t)(c0 + j0 + jj) * R + r0 + i2] = f2bf(tile[i2][j0 + jj]);
}

// ---------------------------------------------------------------------------
// Main GEMM: C[M][N] = concat_parts(A)[M][K] @ BT[N][K]^T + bias.
// 128x128 tile, BK=32, 4 waves each 64x64 (4x4 mfma 16x16x32).
// A: f32 (a_f32=1) or bf16; staged to bf16 LDS. BT: bf16 (preprocessed).
// When astride==256, part p=k0>>8 selects A0/A1/A2 (row stride 256); else A0.
// mode: 0 = bf16 store C[M][N]; 1 = relu+bf16 store; 2 = scatter bf16 into
// V-transpose layout vhT[b][h][d][k] (row=k*16+b, col=h*32+d).
// ---------------------------------------------------------------------------
#define APAD 40
__global__ __launch_bounds__(256) void gemm_bt(
    const void* __restrict__ A0v, const void* __restrict__ A1v, const void* __restrict__ A2v,
    int astride, int a_f32, const u16* __restrict__ BT, const float* __restrict__ bias,
    u16* __restrict__ C, int M, int N, int K, int mode) {
    __shared__ u16 As[128 * APAD];
    __shared__ u16 Bs[128 * APAD];
    int tid = threadIdx.x;
    int wave = tid >> 6, lane = tid & 63;
    int l15 = lane & 15, quad = lane >> 4;
    int wm = (wave >> 1) * 64, wn = (wave & 1) * 64;
    int gm0 = blockIdx.x * 128, gn0 = blockIdx.y * 128;
    f32x4 acc[4][4] = {};
    for (int k0 = 0; k0 < K; k0 += 32) {
        const void* ap;
        int kin;
        if (astride == 256) {
            int p = k0 >> 8;
            ap = (p == 0) ? A0v : ((p == 1) ? A1v : A2v);
            kin = k0 & 255;
        } else {
            ap = A0v;
            kin = k0;
        }
#pragma unroll
        for (int i = 0; i < 2; i++) {
            int idx = tid * 2 + i;
            int row = idx >> 2, seg = (idx & 3) * 8;
            int grow = gm0 + row;
            u16 tmp[8];
            if (a_f32) {
                float vv[8] = {0.f, 0.f, 0.f, 0.f, 0.f, 0.f, 0.f, 0.f};
                if (grow < M) {
                    const float* apf = (const float*)ap;
                    float4 u0 = *(const float4*)(apf + (size_t)grow * astride + kin + seg);
                    float4 u1 = *(const float4*)(apf + (size_t)grow * astride + kin + seg + 4);
                    vv[0] = u0.x; vv[1] = u0.y; vv[2] = u0.z; vv[3] = u0.w;
                    vv[4] = u1.x; vv[5] = u1.y; vv[6] = u1.z; vv[7] = u1.w;
                }
#pragma unroll
                for (int e = 0; e < 8; e++) tmp[e] = f2bf(vv[e]);
            } else {
                uint4 v;
                v.x = v.y = v.z = v.w = 0;
                if (grow < M) v = *(const uint4*)((const u16*)ap + (size_t)grow * astride + kin + seg);
                *(uint4*)tmp = v;
            }
            *(uint4*)(&As[row * APAD + seg]) = *(uint4*)tmp;
            int nrow = gn0 + row;
            uint4 w = *(const uint4*)(BT + (size_t)nrow * K + k0 + seg);
            *(uint4*)(&Bs[row * APAD + seg]) = w;
        }
        __syncthreads();
        short8 afr[4], bfr[4];
#pragma unroll
        for (int i = 0; i < 4; i++)
            afr[i] = *(const short8*)(&As[(wm + i * 16 + l15) * APAD + quad * 8]);
#pragma unroll
        for (int j = 0; j < 4; j++)
            bfr[j] = *(const short8*)(&Bs[(wn + j * 16 + l15) * APAD + quad * 8]);
#pragma unroll
        for (int i = 0; i < 4; i++)
#pragma unroll
            for (int j = 0; j < 4; j++) acc[i][j] = MFMA16(afr[i], bfr[j], acc[i][j]);
        __syncthreads();
    }
#pragma unroll
    for (int i = 0; i < 4; i++) {
        int row = gm0 + wm + i * 16 + quad * 4;
#pragma unroll
        for (int j = 0; j < 4; j++) {
            int col = gn0 + wn + j * 16 + l15;
            float bvv = bias[col];
#pragma unroll
            for (int r = 0; r < 4; r++) {
                int grow = row + r;
                if (grow < M) {
                    float v = acc[i][j][r] + bvv;
                    if (mode == 1) v = fmaxf(v, 0.f);
                    if (mode == 2) {
                        int kk = grow >> 4, bb = grow & 15;
                        int hh = col >> 5, dd = col & 31;
                        C[(((size_t)bb * 8 + hh) * 32 + dd) * 2048 + kk] = f2bf(v);
                    } else {
                        C[(size_t)grow * N + col] = f2bf(v);
                    }
                }
            }
        }
    }
}

// ---------------------------------------------------------------------------
// Attention kernel A: per (qtile, h, b) — one pass over k: unnormalized
// exp-sum Z and unnormalized ctx (logits tiny -> no max subtraction needed);
// normalize in epilogue, store ctx (bf16) and 1/(8Z) (f32).
// ---------------------------------------------------------------------------
__global__ __launch_bounds__(256) void attn_a(const u16* __restrict__ qh,
                                              const u16* __restrict__ kh,
                                              const u16* __restrict__ vhT,
                                              u16* __restrict__ ctxbuf,
                                              float* __restrict__ z8inv) {
    int qt = blockIdx.x, h = blockIdx.y, b = blockIdx.z;
    __shared__ u16 Qt[64 * 72];
    __shared__ u16 Kc[128 * 72];
    __shared__ u16 Pt[64 * 136];
    __shared__ u16 VTc[32 * 136];
    int tid = threadIdx.x, wave = tid >> 6, lane = tid & 63;
    int l15 = lane & 15, quad = lane >> 4;
    int q0 = qt * 64;
#pragma unroll
    for (int i = 0; i < 2; i++) {
        int idx = tid * 2 + i;
        int row = idx >> 3, seg = (idx & 7) * 8;
        uint4 v;
        v.x = v.y = v.z = v.w = 0;
        int q = q0 + row;
        if (q < 300) v = *(const uint4*)(qh + ((size_t)q * 16 + b) * 512 + h * 64 + seg);
        *(uint4*)(&Qt[row * 72 + seg]) = v;
    }
    const f32x4 zf = {0.f, 0.f, 0.f, 0.f};
    f32x4 cacc[2] = {};
    float zrow[4] = {0.f, 0.f, 0.f, 0.f};
    for (int kc0 = 0; kc0 < 2048; kc0 += 128) {
#pragma unroll
        for (int i = 0; i < 4; i++) {
            int idx = tid * 4 + i;
            int row = idx >> 3, seg = (idx & 7) * 8;
            *(uint4*)(&Kc[row * 72 + seg]) =
                *(const uint4*)(kh + ((size_t)(kc0 + row) * 16 + b) * 512 + h * 64 + seg);
        }
#pragma unroll
        for (int i = 0; i < 2; i++) {
            int idx = tid * 2 + i;
            int row = idx >> 4, seg = (idx & 15) * 8;
            *(uint4*)(&VTc[row * 136 + seg]) =
                *(const uint4*)(vhT + (((size_t)b * 8 + h) * 32 + row) * 2048 + kc0 + seg);
        }
        __syncthreads();
        f32x4 sacc[8];
#pragma unroll
        for (int t = 0; t < 8; t++) sacc[t] = zf;
#pragma unroll
        for (int d0 = 0; d0 < 64; d0 += 32) {
            short8 af = *(const short8*)(&Qt[(wave * 16 + l15) * 72 + d0 + quad * 8]);
#pragma unroll
            for (int t = 0; t < 8; t++) {
                short8 bf = *(const short8*)(&Kc[(t * 16 + l15) * 72 + d0 + quad * 8]);
                sacc[t] = MFMA16(af, bf, sacc[t]);
            }
        }
#pragma unroll
        for (int t = 0; t < 8; t++) {
#pragma unroll
            for (int r = 0; r < 4; r++) {
                float p = __expf(sacc[t][r]);
                zrow[r] += p;
                Pt[(wave * 16 + quad * 4 + r) * 136 + t * 16 + l15] = f2bf(p);
            }
        }
#pragma unroll
        for (int kk0 = 0; kk0 < 128; kk0 += 32) {
            short8 af = *(const short8*)(&Pt[(wave * 16 + l15) * 136 + kk0 + quad * 8]);
#pragma unroll
            for (int t = 0; t < 2; t++) {
                short8 bf = *(const short8*)(&VTc[(t * 16 + l15) * 136 + kk0 + quad * 8]);
                cacc[t] = MFMA16(af, bf, cacc[t]);
            }
        }
        __syncthreads();
    }
#pragma unroll
    for (int r = 0; r < 4; r++) {
        float z = zrow[r];
        z += __shfl_xor(z, 1);
        z += __shfl_xor(z, 2);
        z += __shfl_xor(z, 4);
        z += __shfl_xor(z, 8);
        zrow[r] = z;
    }
#pragma unroll
    for (int r = 0; r < 4; r++) {
        int q = q0 + wave * 16 + quad * 4 + r;
        if (q < 300) {
            float rz = 1.0f / zrow[r];
#pragma unroll
            for (int t = 0; t < 2; t++)
                ctxbuf[((size_t)q * 16 + b) * 256 + h * 32 + t * 16 + l15] = f2bf(cacc[t][r] * rz);
            if (l15 == 0) z8inv[((size_t)b * 8 + h) * 320 + q] = rz * 0.125f;
        }
    }
}

// ---------------------------------------------------------------------------
// Attention kernel B: per (kchunk, qtile, b) — loop all 8 heads, recompute
// logits, p = exp(s) * (1/(8Z)), accumulate head-average, write attn_avg (f32).
// ---------------------------------------------------------------------------
__global__ __launch_bounds__(256) void attn_b(const u16* __restrict__ qh,
                                              const u16* __restrict__ kh,
                                              const float* __restrict__ z8inv,
                                              float* __restrict__ out1) {
    int kc0 = blockIdx.x * 128, qt = blockIdx.y, b = blockIdx.z;
    __shared__ u16 Qt[64 * 72];
    __shared__ u16 Kc[128 * 72];
    int tid = threadIdx.x, wave = tid >> 6, lane = tid & 63;
    int l15 = lane & 15, quad = lane >> 4;
    int q0 = qt * 64;
    const f32x4 zf = {0.f, 0.f, 0.f, 0.f};
    float avg[8][4] = {};
    for (int h = 0; h < 8; h++) {
#pragma unroll
        for (int i = 0; i < 2; i++) {
            int idx = tid * 2 + i;
            int row = idx >> 3, seg = (idx & 7) * 8;
            uint4 v;
            v.x = v.y = v.z = v.w = 0;
            int q = q0 + row;
            if (q < 300) v = *(const uint4*)(qh + ((size_t)q * 16 + b) * 512 + h * 64 + seg);
            *(uint4*)(&Qt[row * 72 + seg]) = v;
        }
#pragma unroll
        for (int i = 0; i < 4; i++) {
            int idx = tid * 4 + i;
            int row = idx >> 3, seg = (idx & 7) * 8;
            *(uint4*)(&Kc[row * 72 + seg]) =
                *(const uint4*)(kh + ((size_t)(kc0 + row) * 16 + b) * 512 + h * 64 + seg);
        }
        __syncthreads();
        f32x4 sacc[8];
#pragma unroll
        for (int t = 0; t < 8; t++) sacc[t] = zf;
#pragma unroll
        for (int d0 = 0; d0 < 64; d0 += 32) {
            short8 af = *(const short8*)(&Qt[(wave * 16 + l15) * 72 + d0 + quad * 8]);
#pragma unroll
            for (int t = 0; t < 8; t++) {
                short8 bf = *(const short8*)(&Kc[(t * 16 + l15) * 72 + d0 + quad * 8]);
                sacc[t] = MFMA16(af, bf, sacc[t]);
            }
        }
        float zi[4];
#pragma unroll
        for (int r = 0; r < 4; r++) {
            int q = q0 + wave * 16 + quad * 4 + r;
            zi[r] = z8inv[((size_t)b * 8 + h) * 320 + (q < 319 ? q : 319)];
        }
#pragma unroll
        for (int t = 0; t < 8; t++)
#pragma unroll
            for (int r = 0; r < 4; r++) avg[t][r] += __expf(sacc[t][r]) * zi[r];
        __syncthreads();
    }
#pragma unroll
    for (int r = 0; r < 4; r++) {
        int q = q0 + wave * 16 + quad * 4 + r;
        if (q < 300) {
#pragma unroll
            for (int t = 0; t < 8; t++)
                out1[((size_t)b * 300 + q) * 2048 + kc0 + t * 16 + l15] = avg[t][r];
        }
    }
}

// residual add + LayerNorm over last dim (256). a: f32 or bf16; out: f32 or bf16.
__global__ __launch_bounds__(256) void ln_kernel(const void* __restrict__ a, int a_f32,
                                                 const u16* __restrict__ bres,
                                                 const float* __restrict__ g,
                                                 const float* __restrict__ be,
                                                 void* __restrict__ out, int out_f32) {
    int row = blockIdx.x, t = threadIdx.x;
    float av = a_f32 ? ((const float*)a)[(size_t)row * 256 + t]
                     : bf2f(((const u16*)a)[(size_t)row * 256 + t]);
    float v = av + bf2f(bres[(size_t)row * 256 + t]);
    float s = v, sq = v * v;
#pragma unroll
    for (int o = 32; o; o >>= 1) {
        s += __shfl_xor(s, o);
        sq += __shfl_xor(sq, o);
    }
    __shared__ float red[8];
    int wave = t >> 6, lane = t & 63;
    if (lane == 0) {
        red[wave] = s;
        red[4 + wave] = sq;
    }
    __syncthreads();
    s = red[0] + red[1] + red[2] + red[3];
    sq = red[4] + red[5] + red[6] + red[7];
    float mean = s * (1.f / 256.f);
    float var = sq * (1.f / 256.f) - mean * mean;
    float rs = rsqrtf(var + 1e-5f);
    float res = (v - mean) * rs * g[t] + be[t];
    if (out_f32) ((float*)out)[(size_t)row * 256 + t] = res;
    else ((u16*)out)[(size_t)row * 256 + t] = f2bf(res);
}

// ---------------------------------------------------------------------------
extern "C" void kernel_launch(void* const* d_in, const int* in_sizes, int n_in,
                              void* d_out, int out_size, void* d_ws, size_t ws_size,
                              hipStream_t stream) {
    (void)in_sizes; (void)n_in; (void)out_size; (void)ws_size;
    const float* tgt = (const float*)d_in[0];
    const float* mem = (const float*)d_in[1];
    const float* pos = (const float*)d_in[2];
    const float* qpos = (const float*)d_in[3];
    const float* qsine = (const float*)d_in[4];
    const float* w_qc = (const float*)d_in[5];
    const float* b_qc = (const float*)d_in[6];
    const float* w_qp = (const float*)d_in[7];
    const float* b_qp = (const float*)d_in[8];
    const float* w_kc = (const float*)d_in[9];
    const float* b_kc = (const float*)d_in[10];
    const float* w_kp = (const float*)d_in[11];
    const float* b_kp = (const float*)d_in[12];
    const float* w_v = (const float*)d_in[13];
    const float* b_v = (const float*)d_in[14];
    const float* w_qs = (const float*)d_in[15];
    const float* b_qs = (const float*)d_in[16];
    const float* wq = (const float*)d_in[17];
    const float* bq = (const float*)d_in[18];
    const float* wk = (const float*)d_in[19];
    const float* bk = (const float*)d_in[20];
    const float* wv_w = (const float*)d_in[21];
    const float* bv = (const float*)d_in[22];
    const float* wo = (const float*)d_in[23];
    const float* bo = (const float*)d_in[24];
    const float* w1 = (const float*)d_in[25];
    const float* b1 = (const float*)d_in[26];
    const float* w2 = (const float*)d_in[27];
    const float* b2 = (const float*)d_in[28];
    const float* g2 = (const float*)d_in[29];
    const float* be2 = (const float*)d_in[30];
    const float* g3 = (const float*)d_in[31];
    const float* be3 = (const float*)d_in[32];

    // --- workspace layout (peak 0x2B58000 = 45.6 MB) ---
    char* ws = (char*)d_ws;
    u16* WQ3T = (u16*)(ws + 0x000000);     // 512x768 bf16   (0xC0000)
    u16* WK2T = (u16*)(ws + 0x0C0000);     // 512x512        (0x80000)
    u16* WV2T = (u16*)(ws + 0x140000);     // 256x256        (0x20000)
    u16* WOT  = (u16*)(ws + 0x160000);     // 256x256        (0x20000)
    u16* W1T  = (u16*)(ws + 0x180000);     // 2048x256       (0x100000)
    u16* W2T  = (u16*)(ws + 0x280000);     // 256x2048       (0x100000)
    float* BQF = (float*)(ws + 0x380000);
    float* BKF = (float*)(ws + 0x381000);
    float* BVF = (float*)(ws + 0x382000);
    float* Z8  = (float*)(ws + 0x390000);  // 16x8x320 f32   (0x28000)
    u16* QH  = (u16*)(ws + 0x400000);      // [4800][512]    (0x4B0000)
    u16* KH  = (u16*)(ws + 0x900000);      // [32768][512]   (0x2000000) -> 0x2900000
    u16* CTX = (u16*)(ws + 0x2900000);     // [4800][256]    (0x258000)  -> 0x2B58000
    // after attn_b, KH region is dead -> reuse for post-attention buffers:
    u16* TGT2 = (u16*)(ws + 0x900000);     // [4800][256]
    u16* XBUF = (u16*)(ws + 0xB60000);     // [4800][256]
    u16* FFNB = (u16*)(ws + 0xDC0000);     // [4800][256]
    u16* HBUF = (u16*)(ws + 0x1020000);    // [4800][2048]   -> 0x22E0000

    float* out0 = (float*)d_out;
    float* out1 = out0 + 1228800;
    // VHT [16][8][32][2048] bf16 (16 MB) lives in out1's region (39.3 MB f32):
    // written by V-GEMM (mode 2), consumed by attn_a, then attn_b overwrites
    // all of out1 with attn_avg. Stream-ordered, out1 fully rewritten every call.
    u16* VHT = (u16*)out1;

    fold_q<<<dim3(2, 192), 256, 0, stream>>>(w_qc, w_qp, w_qs, wq, WQ3T);
    fold_k<<<dim3(2, 128), 256, 0, stream>>>(w_kc, w_kp, wk, WK2T);
    fold_v<<<dim3(1, 64), 256, 0, stream>>>(w_v, wv_w, WV2T);
    fold_bias<<<20, 256, 0, stream>>>(b_qc, b_qp, b_qs, wq, bq, b_kc, b_kp, wk, bk,
                                      b_v, wv_w, bv, BQF, BKF, BVF);
    transpose_f2b<<<dim3(8, 8), 256, 0, stream>>>(wo, WOT, 256, 256);
    transpose_f2b<<<dim3(64, 8), 256, 0, stream>>>(w1, W1T, 256, 2048);
    transpose_f2b<<<dim3(8, 64), 256, 0, stream>>>(w2, W2T, 2048, 256);

    gemm_bt<<<dim3(38, 4), 256, 0, stream>>>(tgt, qpos, qsine, 256, 1, WQ3T, BQF, QH, 4800, 512, 768, 0);
    gemm_bt<<<dim3(256, 4), 256, 0, stream>>>(mem, pos, nullptr, 256, 1, WK2T, BKF, KH, 32768, 512, 512, 0);
    gemm_bt<<<dim3(256, 2), 256, 0, stream>>>(mem, nullptr, nullptr, 256, 1, WV2T, BVF, VHT, 32768, 256, 256, 2);

    attn_a<<<dim3(5, 8, 16), 256, 0, stream>>>(QH, KH, VHT, CTX, Z8);
    attn_b<<<dim3(16, 5, 16), 256, 0, stream>>>(QH, KH, Z8, out1);

    gemm_bt<<<dim3(38, 2), 256, 0, stream>>>(CTX, nullptr, nullptr, 256, 0, WOT, bo, TGT2, 4800, 256, 256, 0);
    ln_kernel<<<4800, 256, 0, stream>>>(tgt, 1, TGT2, g2, be2, XBUF, 0);
    gemm_bt<<<dim3(38, 16), 256, 0, stream>>>(XBUF, nullptr, nullptr, 256, 0, W1T, b1, HBUF, 4800, 2048, 256, 1);
    gemm_bt<<<dim3(38, 2), 256, 0, stream>>>(HBUF, nullptr, nullptr, 2048, 0, W2T, b2, FFNB, 4800, 256, 2048, 0);
    ln_kernel<<<4800, 256, 0, stream>>>(XBUF, 0, FFNB, g3, be3, out0, 1);
}

// Round 6
// 589.888 us; speedup vs baseline: 1.5160x; 1.1089x over previous
//
#include <hip/hip_runtime.h>

typedef unsigned short u16;
typedef __attribute__((ext_vector_type(8))) short short8;
typedef __attribute__((ext_vector_type(4))) float f32x4;

#define MFMA16(a, b, c) __builtin_amdgcn_mfma_f32_16x16x32_bf16(a, b, c, 0, 0, 0)

__device__ __forceinline__ float bf2f(u16 u) {
    return __uint_as_float(((unsigned)u) << 16);
}
__device__ __forceinline__ u16 f2bf(float f) {
    unsigned u = __float_as_uint(f);
    u += 0x7fff + ((u >> 16) & 1);
    return (u16)(u >> 16);
}

// convert mem & pos (f32, 8388608 elems each) to bf16. grid 8192 x 256.
__global__ __launch_bounds__(256) void cvt2(const float* __restrict__ a,
                                            const float* __restrict__ b,
                                            u16* __restrict__ A, u16* __restrict__ B) {
    size_t i = ((size_t)blockIdx.x * 256 + threadIdx.x) * 4;
    float4 va = *(const float4*)(a + i);
    float4 vb = *(const float4*)(b + i);
    u16 ta[4] = {f2bf(va.x), f2bf(va.y), f2bf(va.z), f2bf(va.w)};
    u16 tb[4] = {f2bf(vb.x), f2bf(vb.y), f2bf(vb.z), f2bf(vb.w)};
    *(uint2*)(A + i) = *(uint2*)ta;
    *(uint2*)(B + i) = *(uint2*)tb;
}

// ---------------------------------------------------------------------------
// Fold kernels v3: collapse (proj -> concat -> proj) into bf16 weights stored
// TRANSPOSED ([N][K]). One thread per o (lane-coalesced wq/wk/wv column
// reads), 4 k-outputs per thread; wsrc[k][c] block-uniform -> scalar loads.
// Head-concat col map: mapC(c)=(c>>5)*64+(c&31), mapS=mapC+32.
// ---------------------------------------------------------------------------

// WQ3T[512][768]: k<256: w_qc@wqC ; 256..511: w_qp@wqC ; 512..767: w_qs@wqS (x 1/8)
__global__ __launch_bounds__(256) void fold_q(const float* __restrict__ w_qc,
                                              const float* __restrict__ w_qp,
                                              const float* __restrict__ w_qs,
                                              const float* __restrict__ wq,
                                              u16* __restrict__ WQ3T) {
    int o = blockIdx.x * 256 + threadIdx.x;
    int k0 = blockIdx.y * 4;
    int seg = k0 >> 8, kb = k0 & 255;
    const float* wsrc = (seg == 0) ? w_qc : ((seg == 1) ? w_qp : w_qs);
    int sOff = (seg == 2) ? 32 : 0;
    const float* wcol = wq + o;
    float acc[4] = {0.f, 0.f, 0.f, 0.f};
#pragma unroll 8
    for (int c = 0; c < 256; c++) {
        int mc = (c >> 5) * 64 + (c & 31) + sOff;
        float w0 = wcol[(size_t)mc * 512];
#pragma unroll
        for (int j = 0; j < 4; j++)
            acc[j] += wsrc[(size_t)(kb + j) * 256 + c] * w0;
    }
    u16 outv[4];
#pragma unroll
    for (int j = 0; j < 4; j++) outv[j] = f2bf(acc[j] * 0.125f);
    *(uint2*)(WQ3T + (size_t)o * 768 + k0) = *(uint2*)outv;
}

// WK2T[512][512]: k<256: w_kc@wkC ; k>=256: w_kp@(wkC+wkS)
__global__ __launch_bounds__(256) void fold_k(const float* __restrict__ w_kc,
                                              const float* __restrict__ w_kp,
                                              const float* __restrict__ wk,
                                              u16* __restrict__ WK2T) {
    int o = blockIdx.x * 256 + threadIdx.x;
    int k0 = blockIdx.y * 4;
    bool second = k0 >= 256;
    int kb = second ? k0 - 256 : k0;
    const float* wcol = wk + o;
    float acc[4] = {0.f, 0.f, 0.f, 0.f};
    if (second) {
#pragma unroll 8
        for (int c = 0; c < 256; c++) {
            int mc = (c >> 5) * 64 + (c & 31);
            float w0 = wcol[(size_t)mc * 512] + wcol[(size_t)(mc + 32) * 512];
#pragma unroll
            for (int j = 0; j < 4; j++)
                acc[j] += w_kp[(size_t)(kb + j) * 256 + c] * w0;
        }
    } else {
#pragma unroll 8
        for (int c = 0; c < 256; c++) {
            int mc = (c >> 5) * 64 + (c & 31);
            float w0 = wcol[(size_t)mc * 512];
#pragma unroll
            for (int j = 0; j < 4; j++)
                acc[j] += w_kc[(size_t)(kb + j) * 256 + c] * w0;
        }
    }
    u16 outv[4];
#pragma unroll
    for (int j = 0; j < 4; j++) outv[j] = f2bf(acc[j]);
    *(uint2*)(WK2T + (size_t)o * 512 + k0) = *(uint2*)outv;
}

// WV2T[256][256] = (w_v @ wv)^T ; grid (1, 64), block 256
__global__ __launch_bounds__(256) void fold_v(const float* __restrict__ w_v,
                                              const float* __restrict__ wv_w,
                                              u16* __restrict__ WV2T) {
    int o = threadIdx.x;
    int k0 = blockIdx.y * 4;
    float acc[4] = {0.f, 0.f, 0.f, 0.f};
#pragma unroll 8
    for (int c = 0; c < 256; c++) {
        float w0 = wv_w[(size_t)c * 256 + o];
#pragma unroll
        for (int j = 0; j < 4; j++)
            acc[j] += w_v[(size_t)(k0 + j) * 256 + c] * w0;
    }
    u16 outv[4];
#pragma unroll
    for (int j = 0; j < 4; j++) outv[j] = f2bf(acc[j]);
    *(uint2*)(WV2T + (size_t)o * 256 + k0) = *(uint2*)outv;
}

// folded biases (f32): BQF[512], BKF[512], BVF[256]. grid 20 blocks.
__global__ __launch_bounds__(256) void fold_bias(
    const float* b_qc, const float* b_qp, const float* b_qs, const float* wq, const float* bq,
    const float* b_kc, const float* b_kp, const float* wk, const float* bk,
    const float* b_v, const float* wv_w, const float* bv,
    float* BQF, float* BKF, float* BVF) {
    __shared__ float red[4][64];
    int tid = threadIdx.x, lane = tid & 63, wave = tid >> 6;
    int blk = blockIdx.x;
    float acc = 0.f;
    if (blk < 8) {
        int o = blk * 64 + lane;
#pragma unroll 4
        for (int c = wave * 64; c < wave * 64 + 64; c++) {
            int mc = (c >> 5) * 64 + (c & 31);
            acc += (b_qc[c] + b_qp[c]) * wq[(size_t)mc * 512 + o];
            acc += b_qs[c] * wq[(size_t)(mc + 32) * 512 + o];
        }
        red[wave][lane] = acc;
        __syncthreads();
        if (wave == 0)
            BQF[o] = (bq[o] + red[0][lane] + red[1][lane] + red[2][lane] + red[3][lane]) * 0.125f;
    } else if (blk < 16) {
        int o = (blk - 8) * 64 + lane;
#pragma unroll 4
        for (int c = wave * 64; c < wave * 64 + 64; c++) {
            int mc = (c >> 5) * 64 + (c & 31);
            acc += (b_kc[c] + b_kp[c]) * wk[(size_t)mc * 512 + o];
            acc += b_kp[c] * wk[(size_t)(mc + 32) * 512 + o];
        }
        red[wave][lane] = acc;
        __syncthreads();
        if (wave == 0)
            BKF[o] = bk[o] + red[0][lane] + red[1][lane] + red[2][lane] + red[3][lane];
    } else {
        int o = (blk - 16) * 64 + lane;
#pragma unroll 4
        for (int c = wave * 64; c < wave * 64 + 64; c++)
            acc += b_v[c] * wv_w[(size_t)c * 256 + o];
        red[wave][lane] = acc;
        __syncthreads();
        if (wave == 0)
            BVF[o] = bv[o] + red[0][lane] + red[1][lane] + red[2][lane] + red[3][lane];
    }
}

// f32 -> bf16 transpose: dst[C][R] = src[R][C], 32x32 tiles
__global__ __launch_bounds__(256) void transpose_f2b(const float* __restrict__ src,
                                                     u16* __restrict__ dst, int R, int C) {
    __shared__ float tile[32][33];
    int c0 = blockIdx.x * 32, r0 = blockIdx.y * 32;
    int t = threadIdx.x;
    int j = t & 31, i0 = (t >> 5) * 4;
#pragma unroll
    for (int ii = 0; ii < 4; ii++)
        tile[i0 + ii][j] = src[(size_t)(r0 + i0 + ii) * C + c0 + j];
    __syncthreads();
    int i2 = t & 31, j0 = (t >> 5) * 4;
#pragma unroll
    for (int jj = 0; jj < 4; jj++)
        dst[(size_t)(c0 + j0 + jj) * R + r0 + i2] = f2bf(tile[i2][j0 + jj]);
}

// ---------------------------------------------------------------------------
// Main GEMM: C[M][N] = concat_parts(A)[M][K] @ BT[N][K]^T + bias.
// 128x128 tile, BK=32, 4 waves each 64x64 (4x4 mfma 16x16x32).
// A: f32 (a_f32=1) or bf16; staged to bf16 LDS. BT: bf16 (preprocessed).
// When astride==256, part p=k0>>8 selects A0/A1/A2 (row stride 256); else A0.
// mode: 0 = bf16 store C[M][N]; 1 = relu then store.
// ---------------------------------------------------------------------------
#define APAD 40
__global__ __launch_bounds__(256) void gemm_bt(
    const void* __restrict__ A0v, const void* __restrict__ A1v, const void* __restrict__ A2v,
    int astride, int a_f32, const u16* __restrict__ BT, const float* __restrict__ bias,
    u16* __restrict__ C, int M, int N, int K, int mode) {
    __shared__ u16 As[128 * APAD];
    __shared__ u16 Bs[128 * APAD];
    int tid = threadIdx.x;
    int wave = tid >> 6, lane = tid & 63;
    int l15 = lane & 15, quad = lane >> 4;
    int wm = (wave >> 1) * 64, wn = (wave & 1) * 64;
    int gm0 = blockIdx.x * 128, gn0 = blockIdx.y * 128;
    f32x4 acc[4][4] = {};
    for (int k0 = 0; k0 < K; k0 += 32) {
        const void* ap;
        int kin;
        if (astride == 256) {
            int p = k0 >> 8;
            ap = (p == 0) ? A0v : ((p == 1) ? A1v : A2v);
            kin = k0 & 255;
        } else {
            ap = A0v;
            kin = k0;
        }
#pragma unroll
        for (int i = 0; i < 2; i++) {
            int idx = tid * 2 + i;
            int row = idx >> 2, seg = (idx & 3) * 8;
            int grow = gm0 + row;
            u16 tmp[8];
            if (a_f32) {
                float vv[8] = {0.f, 0.f, 0.f, 0.f, 0.f, 0.f, 0.f, 0.f};
                if (grow < M) {
                    const float* apf = (const float*)ap;
                    float4 u0 = *(const float4*)(apf + (size_t)grow * astride + kin + seg);
                    float4 u1 = *(const float4*)(apf + (size_t)grow * astride + kin + seg + 4);
                    vv[0] = u0.x; vv[1] = u0.y; vv[2] = u0.z; vv[3] = u0.w;
                    vv[4] = u1.x; vv[5] = u1.y; vv[6] = u1.z; vv[7] = u1.w;
                }
#pragma unroll
                for (int e = 0; e < 8; e++) tmp[e] = f2bf(vv[e]);
            } else {
                uint4 v;
                v.x = v.y = v.z = v.w = 0;
                if (grow < M) v = *(const uint4*)((const u16*)ap + (size_t)grow * astride + kin + seg);
                *(uint4*)tmp = v;
            }
            *(uint4*)(&As[row * APAD + seg]) = *(uint4*)tmp;
            int nrow = gn0 + row;
            uint4 w = *(const uint4*)(BT + (size_t)nrow * K + k0 + seg);
            *(uint4*)(&Bs[row * APAD + seg]) = w;
        }
        __syncthreads();
        short8 afr[4], bfr[4];
#pragma unroll
        for (int i = 0; i < 4; i++)
            afr[i] = *(const short8*)(&As[(wm + i * 16 + l15) * APAD + quad * 8]);
#pragma unroll
        for (int j = 0; j < 4; j++)
            bfr[j] = *(const short8*)(&Bs[(wn + j * 16 + l15) * APAD + quad * 8]);
#pragma unroll
        for (int i = 0; i < 4; i++)
#pragma unroll
            for (int j = 0; j < 4; j++) acc[i][j] = MFMA16(afr[i], bfr[j], acc[i][j]);
        __syncthreads();
    }
#pragma unroll
    for (int i = 0; i < 4; i++) {
        int row = gm0 + wm + i * 16 + quad * 4;
#pragma unroll
        for (int j = 0; j < 4; j++) {
            int col = gn0 + wn + j * 16 + l15;
            float bvv = bias[col];
#pragma unroll
            for (int r = 0; r < 4; r++) {
                int grow = row + r;
                if (grow < M) {
                    float v = acc[i][j][r] + bvv;
                    if (mode == 1) v = fmaxf(v, 0.f);
                    C[(size_t)grow * N + col] = f2bf(v);
                }
            }
        }
    }
}

// ---------------------------------------------------------------------------
// Attention kernel A: per (qtile, h, b) — one pass over k: unnormalized
// exp-sum Z and unnormalized ctx; normalize in epilogue, store ctx (bf16)
// and 1/(8Z). V read from VHR [k*16+b][256] with in-LDS transpose.
// ---------------------------------------------------------------------------
__global__ __launch_bounds__(256) void attn_a(const u16* __restrict__ qh,
                                              const u16* __restrict__ kh,
                                              const u16* __restrict__ vhr,
                                              u16* __restrict__ ctxbuf,
                                              float* __restrict__ z8inv) {
    int qt = blockIdx.x, h = blockIdx.y, b = blockIdx.z;
    __shared__ u16 Qt[64 * 72];
    __shared__ u16 Kc[128 * 72];
    __shared__ u16 Pt[64 * 136];
    __shared__ u16 VTc[32 * 136];
    int tid = threadIdx.x, wave = tid >> 6, lane = tid & 63;
    int l15 = lane & 15, quad = lane >> 4;
    int q0 = qt * 64;
#pragma unroll
    for (int i = 0; i < 2; i++) {
        int idx = tid * 2 + i;
        int row = idx >> 3, seg = (idx & 7) * 8;
        uint4 v;
        v.x = v.y = v.z = v.w = 0;
        int q = q0 + row;
        if (q < 300) v = *(const uint4*)(qh + ((size_t)q * 16 + b) * 512 + h * 64 + seg);
        *(uint4*)(&Qt[row * 72 + seg]) = v;
    }
    const f32x4 zf = {0.f, 0.f, 0.f, 0.f};
    f32x4 cacc[2] = {};
    float zrow[4] = {0.f, 0.f, 0.f, 0.f};
    for (int kc0 = 0; kc0 < 2048; kc0 += 128) {
#pragma unroll
        for (int i = 0; i < 4; i++) {
            int idx = tid * 4 + i;
            int row = idx >> 3, seg = (idx & 7) * 8;
            *(uint4*)(&Kc[row * 72 + seg]) =
                *(const uint4*)(kh + ((size_t)(kc0 + row) * 16 + b) * 512 + h * 64 + seg);
        }
        // V tile [128 k][32 d] -> VTc[d][k] via in-LDS transpose
#pragma unroll
        for (int i = 0; i < 2; i++) {
            int idx = tid * 2 + i;
            int kk = idx >> 2, dseg = (idx & 3) * 8;
            u16 tmp[8];
            *(uint4*)tmp = *(const uint4*)(vhr + ((size_t)(kc0 + kk) * 16 + b) * 256 + h * 32 + dseg);
#pragma unroll
            for (int e = 0; e < 8; e++) VTc[(dseg + e) * 136 + kk] = tmp[e];
        }
        __syncthreads();
        f32x4 sacc[8];
#pragma unroll
        for (int t = 0; t < 8; t++) sacc[t] = zf;
#pragma unroll
        for (int d0 = 0; d0 < 64; d0 += 32) {
            short8 af = *(const short8*)(&Qt[(wave * 16 + l15) * 72 + d0 + quad * 8]);
#pragma unroll
            for (int t = 0; t < 8; t++) {
                short8 bf = *(const short8*)(&Kc[(t * 16 + l15) * 72 + d0 + quad * 8]);
                sacc[t] = MFMA16(af, bf, sacc[t]);
            }
        }
#pragma unroll
        for (int t = 0; t < 8; t++) {
#pragma unroll
            for (int r = 0; r < 4; r++) {
                float p = __expf(sacc[t][r]);
                zrow[r] += p;
                Pt[(wave * 16 + quad * 4 + r) * 136 + t * 16 + l15] = f2bf(p);
            }
        }
#pragma unroll
        for (int kk0 = 0; kk0 < 128; kk0 += 32) {
            short8 af = *(const short8*)(&Pt[(wave * 16 + l15) * 136 + kk0 + quad * 8]);
#pragma unroll
            for (int t = 0; t < 2; t++) {
                short8 bf = *(const short8*)(&VTc[(t * 16 + l15) * 136 + kk0 + quad * 8]);
                cacc[t] = MFMA16(af, bf, cacc[t]);
            }
        }
        __syncthreads();
    }
#pragma unroll
    for (int r = 0; r < 4; r++) {
        float z = zrow[r];
        z += __shfl_xor(z, 1);
        z += __shfl_xor(z, 2);
        z += __shfl_xor(z, 4);
        z += __shfl_xor(z, 8);
        zrow[r] = z;
    }
#pragma unroll
    for (int r = 0; r < 4; r++) {
        int q = q0 + wave * 16 + quad * 4 + r;
        if (q < 300) {
            float rz = 1.0f / zrow[r];
#pragma unroll
            for (int t = 0; t < 2; t++)
                ctxbuf[((size_t)q * 16 + b) * 256 + h * 32 + t * 16 + l15] = f2bf(cacc[t][r] * rz);
            if (l15 == 0) z8inv[((size_t)b * 8 + h) * 320 + q] = rz * 0.125f;
        }
    }
}

// ---------------------------------------------------------------------------
// Attention kernel B: per (kchunk, qtile, b) — loop all 8 heads, recompute
// logits, p = exp(s) * (1/(8Z)), accumulate head-average, write attn_avg (f32).
// ---------------------------------------------------------------------------
__global__ __launch_bounds__(256) void attn_b(const u16* __restrict__ qh,
                                              const u16* __restrict__ kh,
                                              const float* __restrict__ z8inv,
                                              float* __restrict__ out1) {
    int kc0 = blockIdx.x * 128, qt = blockIdx.y, b = blockIdx.z;
    __shared__ u16 Qt[64 * 72];
    __shared__ u16 Kc[128 * 72];
    int tid = threadIdx.x, wave = tid >> 6, lane = tid & 63;
    int l15 = lane & 15, quad = lane >> 4;
    int q0 = qt * 64;
    const f32x4 zf = {0.f, 0.f, 0.f, 0.f};
    float avg[8][4] = {};
    for (int h = 0; h < 8; h++) {
#pragma unroll
        for (int i = 0; i < 2; i++) {
            int idx = tid * 2 + i;
            int row = idx >> 3, seg = (idx & 7) * 8;
            uint4 v;
            v.x = v.y = v.z = v.w = 0;
            int q = q0 + row;
            if (q < 300) v = *(const uint4*)(qh + ((size_t)q * 16 + b) * 512 + h * 64 + seg);
            *(uint4*)(&Qt[row * 72 + seg]) = v;
        }
#pragma unroll
        for (int i = 0; i < 4; i++) {
            int idx = tid * 4 + i;
            int row = idx >> 3, seg = (idx & 7) * 8;
            *(uint4*)(&Kc[row * 72 + seg]) =
                *(const uint4*)(kh + ((size_t)(kc0 + row) * 16 + b) * 512 + h * 64 + seg);
        }
        __syncthreads();
        f32x4 sacc[8];
#pragma unroll
        for (int t = 0; t < 8; t++) sacc[t] = zf;
#pragma unroll
        for (int d0 = 0; d0 < 64; d0 += 32) {
            short8 af = *(const short8*)(&Qt[(wave * 16 + l15) * 72 + d0 + quad * 8]);
#pragma unroll
            for (int t = 0; t < 8; t++) {
                short8 bf = *(const short8*)(&Kc[(t * 16 + l15) * 72 + d0 + quad * 8]);
                sacc[t] = MFMA16(af, bf, sacc[t]);
            }
        }
        float zi[4];
#pragma unroll
        for (int r = 0; r < 4; r++) {
            int q = q0 + wave * 16 + quad * 4 + r;
            zi[r] = z8inv[((size_t)b * 8 + h) * 320 + (q < 319 ? q : 319)];
        }
#pragma unroll
        for (int t = 0; t < 8; t++)
#pragma unroll
            for (int r = 0; r < 4; r++) avg[t][r] += __expf(sacc[t][r]) * zi[r];
        __syncthreads();
    }
#pragma unroll
    for (int r = 0; r < 4; r++) {
        int q = q0 + wave * 16 + quad * 4 + r;
        if (q < 300) {
#pragma unroll
            for (int t = 0; t < 8; t++)
                out1[((size_t)b * 300 + q) * 2048 + kc0 + t * 16 + l15] = avg[t][r];
        }
    }
}

// residual add + LayerNorm over last dim (256). a: f32 or bf16; out: f32 or bf16.
__global__ __launch_bounds__(256) void ln_kernel(const void* __restrict__ a, int a_f32,
                                                 const u16* __restrict__ bres,
                                                 const float* __restrict__ g,
                                                 const float* __restrict__ be,
                                                 void* __restrict__ out, int out_f32) {
    int row = blockIdx.x, t = threadIdx.x;
    float av = a_f32 ? ((const float*)a)[(size_t)row * 256 + t]
                     : bf2f(((const u16*)a)[(size_t)row * 256 + t]);
    float v = av + bf2f(bres[(size_t)row * 256 + t]);
    float s = v, sq = v * v;
#pragma unroll
    for (int o = 32; o; o >>= 1) {
        s += __shfl_xor(s, o);
        sq += __shfl_xor(sq, o);
    }
    __shared__ float red[8];
    int wave = t >> 6, lane = t & 63;
    if (lane == 0) {
        red[wave] = s;
        red[4 + wave] = sq;
    }
    __syncthreads();
    s = red[0] + red[1] + red[2] + red[3];
    sq = red[4] + red[5] + red[6] + red[7];
    float mean = s * (1.f / 256.f);
    float var = sq * (1.f / 256.f) - mean * mean;
    float rs = rsqrtf(var + 1e-5f);
    float res = (v - mean) * rs * g[t] + be[t];
    if (out_f32) ((float*)out)[(size_t)row * 256 + t] = res;
    else ((u16*)out)[(size_t)row * 256 + t] = f2bf(res);
}

// ---------------------------------------------------------------------------
extern "C" void kernel_launch(void* const* d_in, const int* in_sizes, int n_in,
                              void* d_out, int out_size, void* d_ws, size_t ws_size,
                              hipStream_t stream) {
    (void)in_sizes; (void)n_in; (void)out_size; (void)ws_size;
    const float* tgt = (const float*)d_in[0];
    const float* mem = (const float*)d_in[1];
    const float* pos = (const float*)d_in[2];
    const float* qpos = (const float*)d_in[3];
    const float* qsine = (const float*)d_in[4];
    const float* w_qc = (const float*)d_in[5];
    const float* b_qc = (const float*)d_in[6];
    const float* w_qp = (const float*)d_in[7];
    const float* b_qp = (const float*)d_in[8];
    const float* w_kc = (const float*)d_in[9];
    const float* b_kc = (const float*)d_in[10];
    const float* w_kp = (const float*)d_in[11];
    const float* b_kp = (const float*)d_in[12];
    const float* w_v = (const float*)d_in[13];
    const float* b_v = (const float*)d_in[14];
    const float* w_qs = (const float*)d_in[15];
    const float* b_qs = (const float*)d_in[16];
    const float* wq = (const float*)d_in[17];
    const float* bq = (const float*)d_in[18];
    const float* wk = (const float*)d_in[19];
    const float* bk = (const float*)d_in[20];
    const float* wv_w = (const float*)d_in[21];
    const float* bv = (const float*)d_in[22];
    const float* wo = (const float*)d_in[23];
    const float* bo = (const float*)d_in[24];
    const float* w1 = (const float*)d_in[25];
    const float* b1 = (const float*)d_in[26];
    const float* w2 = (const float*)d_in[27];
    const float* b2 = (const float*)d_in[28];
    const float* g2 = (const float*)d_in[29];
    const float* be2 = (const float*)d_in[30];
    const float* g3 = (const float*)d_in[31];
    const float* be3 = (const float*)d_in[32];

    // --- workspace layout (peak 0x2B58000 = 45.6 MB) ---
    char* ws = (char*)d_ws;
    u16* WQ3T = (u16*)(ws + 0x000000);     // 512x768 bf16   (0xC0000)
    u16* WK2T = (u16*)(ws + 0x0C0000);     // 512x512        (0x80000)
    u16* WV2T = (u16*)(ws + 0x140000);     // 256x256        (0x20000)
    u16* WOT  = (u16*)(ws + 0x160000);     // 256x256        (0x20000)
    u16* W1T  = (u16*)(ws + 0x180000);     // 2048x256       (0x100000)
    u16* W2T  = (u16*)(ws + 0x280000);     // 256x2048       (0x100000)
    float* BQF = (float*)(ws + 0x380000);
    float* BKF = (float*)(ws + 0x381000);
    float* BVF = (float*)(ws + 0x382000);
    float* Z8  = (float*)(ws + 0x390000);  // 16x8x320 f32   (0x28000)
    u16* QH  = (u16*)(ws + 0x400000);      // [4800][512]    (0x4B0000)
    u16* KH  = (u16*)(ws + 0x900000);      // [32768][512]   (0x2000000) -> 0x2900000
    u16* CTX = (u16*)(ws + 0x2900000);     // [4800][256]    (0x258000)  -> 0x2B58000
    // after attn_b, KH region is dead -> reuse for post-attention buffers:
    u16* TGT2 = (u16*)(ws + 0x900000);     // [4800][256]
    u16* XBUF = (u16*)(ws + 0xB60000);     // [4800][256]
    u16* FFNB = (u16*)(ws + 0xDC0000);     // [4800][256]
    u16* HBUF = (u16*)(ws + 0x1020000);    // [4800][2048]   -> 0x22E0000

    float* out0 = (float*)d_out;
    float* out1 = out0 + 1228800;
    // out1 region (39.3 MB) staging, all dead before attn_b overwrites it:
    //   MB  (bf16 mem, 16 MB) @ +0        : cvt2 -> KH & V GEMMs
    //   PB  (bf16 pos, 16 MB) @ +0x1000000: cvt2 -> KH GEMM
    //   VHR (bf16 v,   16 MB) @ +0x1000000: V GEMM -> attn_a (aliases dead PB)
    u16* MB  = (u16*)out1;
    u16* PB  = MB + 8388608;
    u16* VHR = PB;

    cvt2<<<8192, 256, 0, stream>>>(mem, pos, MB, PB);
    fold_q<<<dim3(2, 192), 256, 0, stream>>>(w_qc, w_qp, w_qs, wq, WQ3T);
    fold_k<<<dim3(2, 128), 256, 0, stream>>>(w_kc, w_kp, wk, WK2T);
    fold_v<<<dim3(1, 64), 256, 0, stream>>>(w_v, wv_w, WV2T);
    fold_bias<<<20, 256, 0, stream>>>(b_qc, b_qp, b_qs, wq, bq, b_kc, b_kp, wk, bk,
                                      b_v, wv_w, bv, BQF, BKF, BVF);
    transpose_f2b<<<dim3(8, 8), 256, 0, stream>>>(wo, WOT, 256, 256);
    transpose_f2b<<<dim3(64, 8), 256, 0, stream>>>(w1, W1T, 256, 2048);
    transpose_f2b<<<dim3(8, 64), 256, 0, stream>>>(w2, W2T, 2048, 256);

    gemm_bt<<<dim3(38, 4), 256, 0, stream>>>(tgt, qpos, qsine, 256, 1, WQ3T, BQF, QH, 4800, 512, 768, 0);
    gemm_bt<<<dim3(256, 4), 256, 0, stream>>>(MB, PB, nullptr, 256, 0, WK2T, BKF, KH, 32768, 512, 512, 0);
    gemm_bt<<<dim3(256, 2), 256, 0, stream>>>(MB, nullptr, nullptr, 256, 0, WV2T, BVF, VHR, 32768, 256, 256, 0);

    attn_a<<<dim3(5, 8, 16), 256, 0, stream>>>(QH, KH, VHR, CTX, Z8);
    attn_b<<<dim3(16, 5, 16), 256, 0, stream>>>(QH, KH, Z8, out1);

    gemm_bt<<<dim3(38, 2), 256, 0, stream>>>(CTX, nullptr, nullptr, 256, 0, WOT, bo, TGT2, 4800, 256, 256, 0);
    ln_kernel<<<4800, 256, 0, stream>>>(tgt, 1, TGT2, g2, be2, XBUF, 0);
    gemm_bt<<<dim3(38, 16), 256, 0, stream>>>(XBUF, nullptr, nullptr, 256, 0, W1T, b1, HBUF, 4800, 2048, 256, 1);
    gemm_bt<<<dim3(38, 2), 256, 0, stream>>>(HBUF, nullptr, nullptr, 2048, 0, W2T, b2, FFNB, 4800, 256, 2048, 0);
    ln_kernel<<<4800, 256, 0, stream>>>(XBUF, 0, FFNB, g3, be3, out0, 1);
}